// Round 21
// baseline (319.208 us; speedup 1.0000x reference)
//
#include <hip/hip_runtime.h>
#include <hip/hip_bf16.h>
#include <math.h>

typedef __attribute__((ext_vector_type(8))) short bf16x8;
typedef __attribute__((ext_vector_type(4))) float f32x4;
typedef unsigned short ushort_t;

#define GLOAD(srcp, dstp) __builtin_amdgcn_global_load_lds((const __attribute__((address_space(1))) void*)(srcp), (__attribute__((address_space(3))) void*)(dstp), 16, 0, 0)

// native bf16 convert (RNE)
__device__ inline ushort_t f2bfn(float f){
  union{ __bf16 h; ushort_t u; } c;
  c.h = (__bf16)f;
  return c.u;
}

// ---------------- fp32 -> bf16 convert: ALL four weight mats in one dispatch ----------------
__global__ __launch_bounds__(256) void cvt_all(const float* __restrict__ q, const float* __restrict__ p,
                                               const float* __restrict__ f1, const float* __restrict__ f2w,
                                               ushort_t* __restrict__ dq, ushort_t* __restrict__ dp,
                                               ushort_t* __restrict__ d1, ushort_t* __restrict__ d2){
  int i4 = blockIdx.x*256 + threadIdx.x;
  const float* src; ushort_t* dst; int off;
  if(i4 < 442368){ src=q;  dst=dq; off=i4; }
  else if(i4 < 589824){ src=p;  dst=dp; off=i4-442368; }
  else if(i4 < 1179648){ src=f1; dst=d1; off=i4-589824; }
  else { src=f2w; dst=d2; off=i4-1179648; }
  int i = off*4;
  float4 v = *(const float4*)(src+i);
  ushort4 o; o.x=f2bfn(v.x); o.y=f2bfn(v.y); o.z=f2bfn(v.z); o.w=f2bfn(v.w);
  *(ushort4*)(dst+i) = o;
}

// ---------------- LayerNorm: 192 threads (3 waves), float4 loads, ushort4 stores ----------------
__global__ __launch_bounds__(192) void ln_kernel(const float* __restrict__ x, const float* __restrict__ w,
                                                 const float* __restrict__ b, ushort_t* __restrict__ out){
  int row = blockIdx.x, t = threadIdx.x;
  const float4 v = *(const float4*)(x + (size_t)row*768 + t*4);
  float s  = v.x+v.y+v.z+v.w;
  float s2 = v.x*v.x+v.y*v.y+v.z*v.z+v.w*v.w;
  for(int m=1;m<64;m<<=1){ s += __shfl_xor(s,m,64); s2 += __shfl_xor(s2,m,64); }
  __shared__ float ls[3], ls2[3];
  int wv_ = t>>6;
  if((t&63)==0){ ls[wv_]=s; ls2[wv_]=s2; }
  __syncthreads();
  s = ls[0]+ls[1]+ls[2]; s2 = ls2[0]+ls2[1]+ls2[2];
  float mu = s*(1.f/768.f);
  float var = s2*(1.f/768.f) - mu*mu;
  float rs = rsqrtf(var + 1e-5f);
  float4 wv4 = *(const float4*)(w + t*4);
  float4 bv4 = *(const float4*)(b + t*4);
  ushort4 o;
  o.x = f2bfn((v.x-mu)*rs*wv4.x + bv4.x);
  o.y = f2bfn((v.y-mu)*rs*wv4.y + bv4.y);
  o.z = f2bfn((v.z-mu)*rs*wv4.z + bv4.z);
  o.w = f2bfn((v.w-mu)*rs*wv4.w + bv4.w);
  *(ushort4*)(out + (size_t)row*768 + t*4) = o;
}

// =======================================================================
// 8-phase 256x256 GEMM (T1+T2+T3+T5).
// ROUND-21: LDS 128KB -> 64KB (2 slots/operand) => 2 blocks/CU co-residency.
// Prefetch distance 2 phases: kh1(g) staged in P1(g); kh0(g+1) staged in P3(g);
// mid/end waits vmcnt(0) (slack covered by co-resident block TLP).
// Epilogue: C staged in two 128-row halves (fits 64KB).
// EPI0: qkv scatter; Q block (bn0<768) pre-scaled by c1=0.125*log2e for attn.
// =======================================================================
template<int EPI>
__device__ __forceinline__
void gemm8_body(const ushort_t* __restrict__ A, const ushort_t* __restrict__ BT,
                const float* __restrict__ bias, void* __restrict__ out,
                int K, int Nout, int nBN)
{
  __shared__ ushort_t lds[32768];      // 64 KB
  ushort_t* As = lds;                  // slot h: As + h*8192
  ushort_t* Bs = lds + 16384;
  const int tid = threadIdx.x;
  const int lane = tid & 63, wid = tid >> 6;
  const int wm = wid >> 2, wn = wid & 3;
  const int fq = lane >> 4, fr = lane & 15;

  const int nwg = (int)gridDim.x;
  const int bid = (int)blockIdx.x;
  const int wg = (bid & 7)*(nwg>>3) + (bid>>3);
  const int bm0 = (wg / nBN) << 8;
  const int bn0 = (wg % nBN) << 8;

  const int srow0 = tid >> 2;
  const int srow1 = 128 + srow0;
  const int sgc = ((tid & 3) ^ ((srow0 >> 1) & 3)) << 3;

  auto stageA = [&](int slot, int tile, int kh){
    const int k0 = (tile<<6) + (kh<<5);
    GLOAD(A + (size_t)(bm0 + srow0)*K + k0 + sgc, As + slot*8192 + (wid*64)*8);
    GLOAD(A + (size_t)(bm0 + srow1)*K + k0 + sgc, As + slot*8192 + (512 + wid*64)*8);
  };
  auto stageB = [&](int slot, int tile, int kh){
    const int k0 = (tile<<6) + (kh<<5);
    GLOAD(BT + (size_t)(bn0 + srow0)*K + k0 + sgc, Bs + slot*8192 + (wid*64)*8);
    GLOAD(BT + (size_t)(bn0 + srow1)*K + k0 + sgc, Bs + slot*8192 + (512 + wid*64)*8);
  };

  int aoff[8], boff[4];
  #pragma unroll
  for(int m=0;m<8;m++){ int r = wm*128 + m*16 + fr; aoff[m] = r*32 + ((fq ^ ((r>>1)&3))<<3); }
  #pragma unroll
  for(int n=0;n<4;n++){ int r = wn*64  + n*16 + fr; boff[n] = r*32 + ((fq ^ ((r>>1)&3))<<3); }

  f32x4 acc[8][4];
  #pragma unroll
  for(int m=0;m<8;m++)
    #pragma unroll
    for(int n=0;n<4;n++) acc[m][n] = (f32x4){0.f,0.f,0.f,0.f};

  const int NT = K >> 6;
  stageA(0,0,0); stageB(0,0,0);
  stageA(1,0,1); stageB(1,0,1);
  asm volatile("s_waitcnt vmcnt(4)" ::: "memory");   // kh0 of tile0 landed
  __builtin_amdgcn_s_barrier();

  for(int g=0; g<NT; ++g){
    bf16x8 a[8], b0, b1;

    // ---- phase 1: kh0 (slot0), n{0,1}; stage CURRENT tile kh1 into slot1 (freed end of g-1) ----
    #pragma unroll
    for(int m=0;m<8;m++) a[m] = *(const bf16x8*)(As + aoff[m]);
    b0 = *(const bf16x8*)(Bs + boff[0]);
    b1 = *(const bf16x8*)(Bs + boff[1]);
    if(g >= 1){ stageA(1, g, 1); stageB(1, g, 1); }
    __builtin_amdgcn_s_barrier();
    asm volatile("s_waitcnt lgkmcnt(0)" ::: "memory");
    __builtin_amdgcn_s_setprio(1);
    #pragma unroll
    for(int m=0;m<8;m++){
      acc[m][0] = __builtin_amdgcn_mfma_f32_16x16x32_bf16(a[m], b0, acc[m][0], 0,0,0);
      acc[m][1] = __builtin_amdgcn_mfma_f32_16x16x32_bf16(a[m], b1, acc[m][1], 0,0,0);
    }
    __builtin_amdgcn_s_setprio(0);

    // ---- phase 2: kh0 (slot0), n{2,3} ----
    b0 = *(const bf16x8*)(Bs + boff[2]);
    b1 = *(const bf16x8*)(Bs + boff[3]);
    __builtin_amdgcn_s_barrier();
    asm volatile("s_waitcnt lgkmcnt(0)" ::: "memory");
    __builtin_amdgcn_s_setprio(1);
    #pragma unroll
    for(int m=0;m<8;m++){
      acc[m][2] = __builtin_amdgcn_mfma_f32_16x16x32_bf16(a[m], b0, acc[m][2], 0,0,0);
      acc[m][3] = __builtin_amdgcn_mfma_f32_16x16x32_bf16(a[m], b1, acc[m][3], 0,0,0);
    }
    __builtin_amdgcn_s_setprio(0);
    // mid-group: kh1 (slot1) landed; slot0 readers done
    asm volatile("s_waitcnt vmcnt(0)" ::: "memory");
    __builtin_amdgcn_s_barrier();

    // ---- phase 3: kh1 (slot1), n{0,1}; stage NEXT tile kh0 into slot0 (freed after P2) ----
    #pragma unroll
    for(int m=0;m<8;m++) a[m] = *(const bf16x8*)(As + 8192 + aoff[m]);
    b0 = *(const bf16x8*)(Bs + 8192 + boff[0]);
    b1 = *(const bf16x8*)(Bs + 8192 + boff[1]);
    if(g+1 < NT){ stageA(0, g+1, 0); stageB(0, g+1, 0); }
    __builtin_amdgcn_s_barrier();
    asm volatile("s_waitcnt lgkmcnt(0)" ::: "memory");
    __builtin_amdgcn_s_setprio(1);
    #pragma unroll
    for(int m=0;m<8;m++){
      acc[m][0] = __builtin_amdgcn_mfma_f32_16x16x32_bf16(a[m], b0, acc[m][0], 0,0,0);
      acc[m][1] = __builtin_amdgcn_mfma_f32_16x16x32_bf16(a[m], b1, acc[m][1], 0,0,0);
    }
    __builtin_amdgcn_s_setprio(0);

    // ---- phase 4: kh1 (slot1), n{2,3} ----
    b0 = *(const bf16x8*)(Bs + 8192 + boff[2]);
    b1 = *(const bf16x8*)(Bs + 8192 + boff[3]);
    __builtin_amdgcn_s_barrier();
    asm volatile("s_waitcnt lgkmcnt(0)" ::: "memory");
    __builtin_amdgcn_s_setprio(1);
    #pragma unroll
    for(int m=0;m<8;m++){
      acc[m][2] = __builtin_amdgcn_mfma_f32_16x16x32_bf16(a[m], b0, acc[m][2], 0,0,0);
      acc[m][3] = __builtin_amdgcn_mfma_f32_16x16x32_bf16(a[m], b1, acc[m][3], 0,0,0);
    }
    __builtin_amdgcn_s_setprio(0);
    // end-group: next kh0 (slot0) landed; slot1 readers done
    asm volatile("s_waitcnt vmcnt(0)" ::: "memory");
    __builtin_amdgcn_s_barrier();
  }

  // ---- epilogue: stage C in two 128-row halves (64KB LDS) ----
  const float qscale = 0.18033688f;   // 0.125 * log2(e), folded into Q for attn
  const bool isQ = (EPI==0) && (bn0 < 768);
  const bool isV = (EPI==0) && (bn0 >= 1536);
  for(int h=0; h<2; ++h){
    __syncthreads();
    if(wm == h){
      #pragma unroll
      for(int m=0;m<8;m++){
        #pragma unroll
        for(int n=0;n<4;n++){
          int colL = wn*64 + n*16 + fr;
          float bv = bias[bn0 + colL];
          #pragma unroll
          for(int j=0;j<4;j++){
            int rowL = wm*128 + m*16 + fq*4 + j;
            int lr = rowL & 127;
            float v = acc[m][n][j] + bv;
            if constexpr(EPI==2){
              float u = fminf(v*(1.0f + 0.044715f*v*v), 40.f);
              float e = exp2f(2.3020052f*u);
              v = v*e/(1.0f+e);
            }
            if(isQ) v *= qscale;
            lds[lr*256 + (colL ^ (((lr>>2)&3)<<4))] = f2bfn(v);
          }
        }
      }
    }
    __syncthreads();
    if(!isV){
      #pragma unroll 4
      for(int p=0;p<8;p++){
        int flat = tid + p*512;          // 0..4095
        int row = flat>>5;               // 0..127
        int col = (flat&31)*8;
        bf16x8 v8 = *(const bf16x8*)&lds[row*256 + (col ^ (((row>>2)&3)<<4))];
        int rg = bm0 + h*128 + row;
        if constexpr(EPI==0){
          int colg = bn0 + col;
          int which = colg >= 768 ? 1 : 0;
          int rem = colg - which*768;
          int hh = rem>>6, dh = rem&63;
          int bb = rg>>10, np = rg&1023;
          *(bf16x8*)&((ushort_t*)out)[(((size_t)(which*96 + bb*12 + hh)*1024 + np)<<6) + dh] = v8;
        } else {
          *(bf16x8*)&((ushort_t*)out)[(size_t)rg*(size_t)Nout + bn0 + col] = v8;
        }
      }
    } else {
      #pragma unroll 4
      for(int p=0;p<8;p++){
        int flat = tid + p*512;          // 0..4095
        int dL = flat>>4;                // 0..255
        int t8 = (flat&15)*8;            // 0..120 (stays within half)
        ushort_t tmp[8];
        #pragma unroll
        for(int i=0;i<8;i++){
          int row = t8 + i;
          tmp[i] = lds[row*256 + (dL ^ (((row>>2)&3)<<4))];
        }
        int dg = bn0 - 1536 + dL;
        int hh = dg>>6, dh = dg&63;
        int tok0 = bm0 + h*128 + t8;
        int bb = tok0>>10, np = tok0&1023;
        *(bf16x8*)&((ushort_t*)out)[((size_t)(192 + bb*12 + hh)*65536) + dh*1024 + np] = *(bf16x8*)tmp;
      }
    }
  }
}

__global__ __launch_bounds__(512, 2)
void qkv_gemm8(const ushort_t* __restrict__ A, const ushort_t* __restrict__ BT,
               const float* __restrict__ bias, void* __restrict__ out, int K, int Nout, int nBN)
{ gemm8_body<0>(A, BT, bias, out, K, Nout, nBN); }

__global__ __launch_bounds__(512, 2)
void fc1_gemm8(const ushort_t* __restrict__ A, const ushort_t* __restrict__ BT,
               const float* __restrict__ bias, void* __restrict__ out, int K, int Nout, int nBN)
{ gemm8_body<2>(A, BT, bias, out, K, Nout, nBN); }

// ---------------- 64x128 GEMM (EPI1: +resid fp32) for proj / fc2 — UNCHANGED (verified r16) ----------------
__device__ __forceinline__
void gemm_body_epi1(const ushort_t* __restrict__ A, const ushort_t* __restrict__ BT,
                    const float* __restrict__ bias, const float* __restrict__ resid,
                    float* __restrict__ out, int K, int nBN)
{
  __shared__ ushort_t Asm[4][64*32];
  __shared__ ushort_t Bsm[4][128*32];
  const int nwg = (int)gridDim.x;
  const int bid = (int)blockIdx.x;
  const int wg = (bid & 7)*(nwg>>3) + (bid>>3);
  const int bm0 = (wg / nBN) * 64;
  const int bn0 = (wg % nBN) * 128;
  const int tid = threadIdx.x;
  const int lane = tid & 63;
  const int wid = tid >> 6;
  const int wn = wid;
  const int fq = lane>>4, fr = lane&15;

  const int rA = tid>>2;
  const int cAs = ((tid&3) ^ ((rA>>1)&3))<<3;
  const int r0 = wid*32 + (lane>>2);
  const int r1 = r0 + 16;
  const int cBs = ((lane&3) ^ ((r0>>1)&3))<<3;

  f32x4 acc[4][2];
  for(int m=0;m<4;m++) for(int n=0;n<2;n++) acc[m][n] = (f32x4){0.f,0.f,0.f,0.f};

  auto STAGE = [&](int buf, int k0){
    GLOAD(A  + (size_t)(bm0+rA)*K + k0 + cAs, &Asm[buf][wid*512]);
    GLOAD(BT + (size_t)(bn0+r0)*K + k0 + cBs, &Bsm[buf][(wid*2)*512]);
    GLOAD(BT + (size_t)(bn0+r1)*K + k0 + cBs, &Bsm[buf][(wid*2+1)*512]);
  };

  int aoff[4], boff[2];
  #pragma unroll
  for(int m=0;m<4;m++){ int r = m*16 + fr; aoff[m] = r*32 + ((fq ^ ((r>>1)&3))<<3); }
  #pragma unroll
  for(int n=0;n<2;n++){ int r = wn*32 + n*16 + fr; boff[n] = r*32 + ((fq ^ ((r>>1)&3))<<3); }

  const int NT = K>>5;
  STAGE(0, 0);
  STAGE(1, 32);
  STAGE(2, 64);
  asm volatile("s_waitcnt vmcnt(6)" ::: "memory");
  __builtin_amdgcn_s_barrier();

  int cur = 0;
  for(int kt=0; kt<NT; ++kt){
    if(kt+3 < NT) STAGE((cur+3)&3, (kt+3)<<5);
    bf16x8 af[4], bfr[2];
    #pragma unroll
    for(int m=0;m<4;m++)
      af[m] = *(const bf16x8*)(&Asm[cur][aoff[m]]);
    #pragma unroll
    for(int n=0;n<2;n++)
      bfr[n] = *(const bf16x8*)(&Bsm[cur][boff[n]]);
    #pragma unroll
    for(int m=0;m<4;m++)
      #pragma unroll
      for(int n=0;n<2;n++)
        acc[m][n] = __builtin_amdgcn_mfma_f32_16x16x32_bf16(af[m], bfr[n], acc[m][n], 0,0,0);
    if(kt+1 < NT){
      if(kt+3 < NT)      { asm volatile("s_waitcnt vmcnt(6)" ::: "memory"); }
      else if(kt+2 < NT) { asm volatile("s_waitcnt vmcnt(3)" ::: "memory"); }
      else               { asm volatile("s_waitcnt vmcnt(0)" ::: "memory"); }
      __builtin_amdgcn_s_barrier();
    }
    cur = (cur+1)&3;
  }

  for(int m=0;m<4;m++){
    int row0 = bm0 + m*16 + fq*4;
    for(int n=0;n<2;n++){
      int col = bn0 + wn*32 + n*16 + fr;
      float bv = bias[col];
      for(int j=0;j<4;j++){
        int r = row0 + j;
        float v = acc[m][n][j] + bv + resid[(size_t)r*768 + col];
        out[(size_t)r*768 + col] = v;
      }
    }
  }
}

__global__ __launch_bounds__(256)
void proj_gemm(const ushort_t* __restrict__ A, const ushort_t* __restrict__ BT,
               const float* __restrict__ bias, const float* __restrict__ resid,
               float* __restrict__ out, int K, int nBN)
{ gemm_body_epi1(A, BT, bias, resid, out, K, nBN); }

__global__ __launch_bounds__(256)
void fc2_gemm(const ushort_t* __restrict__ A, const ushort_t* __restrict__ BT,
              const float* __restrict__ bias, const float* __restrict__ resid,
              float* __restrict__ out, int K, int nBN)
{ gemm_body_epi1(A, BT, bias, resid, out, K, nBN); }

// ---------------- Flash attention — STATIC softmax; Q pre-scaled by c1 (qkv epilogue) ----------------
__global__ __launch_bounds__(256)
void attn_kernel(const ushort_t* __restrict__ qkv, ushort_t* __restrict__ outp)
{
  __shared__ ushort_t Ksm[2][64*72];
  __shared__ ushort_t Vt[2][64*72];
  __shared__ ushort_t Psm[4][16*72];
  const int bh = blockIdx.y;
  const int q0 = blockIdx.x*64;
  const int tid = threadIdx.x, lane = tid&63, wid = tid>>6;
  const int fq = lane>>4, fr = lane&15;
  const ushort_t* Qb = qkv + ((size_t)bh*1024)*64;
  const ushort_t* Kb = qkv + ((size_t)(96 + bh)*1024)*64;
  const ushort_t* Vb = qkv + ((size_t)(192 + bh))*65536;

  bf16x8 ones;
  #pragma unroll
  for(int i=0;i<8;i++) ones[i] = (short)0x3F80;

  bf16x8 qf[2];
  {
    int qr = q0 + wid*16 + fr;
    qf[0] = *(const bf16x8*)(Qb + (size_t)qr*64 +      fq*8);
    qf[1] = *(const bf16x8*)(Qb + (size_t)qr*64 + 32 + fq*8);
  }
  f32x4 o[4];
  for(int dt=0;dt<4;dt++) o[dt] = (f32x4){0.f,0.f,0.f,0.f};
  float lrun[4];
  for(int j=0;j<4;j++) lrun[j]=0.f;

  const int sr = tid>>3, sc = (tid&7)*8;

  bf16x8 k0r = *(const bf16x8*)(Kb + (size_t)sr*64 + sc);
  bf16x8 k1r = *(const bf16x8*)(Kb + (size_t)(sr+32)*64 + sc);
  bf16x8 v0r = *(const bf16x8*)(Vb + (size_t)sr*1024 + sc);
  bf16x8 v1r = *(const bf16x8*)(Vb + (size_t)(sr+32)*1024 + sc);
  *(bf16x8*)(Ksm[0] + sr*72 + sc)      = k0r;
  *(bf16x8*)(Ksm[0] + (sr+32)*72 + sc) = k1r;
  *(bf16x8*)(Vt[0]  + sr*72 + sc)      = v0r;
  *(bf16x8*)(Vt[0]  + (sr+32)*72 + sc) = v1r;

  int cur = 0;
  for(int kt=0; kt<16; kt++){
    __syncthreads();
    if(kt+1 < 16){
      int kv1 = (kt+1)*64;
      k0r = *(const bf16x8*)(Kb + (size_t)(kv1+sr)*64 + sc);
      k1r = *(const bf16x8*)(Kb + (size_t)(kv1+sr+32)*64 + sc);
      v0r = *(const bf16x8*)(Vb + (size_t)sr*1024 + kv1 + sc);
      v1r = *(const bf16x8*)(Vb + (size_t)(sr+32)*1024 + kv1 + sc);
    }

    f32x4 s[4];
    for(int ct=0;ct<4;ct++){
      bf16x8 kf0 = *(const bf16x8*)(Ksm[cur] + (ct*16 + fr)*72 +      fq*8);
      bf16x8 kf1 = *(const bf16x8*)(Ksm[cur] + (ct*16 + fr)*72 + 32 + fq*8);
      f32x4 z = (f32x4){0.f,0.f,0.f,0.f};
      z = __builtin_amdgcn_mfma_f32_16x16x32_bf16(qf[0], kf0, z, 0,0,0);
      z = __builtin_amdgcn_mfma_f32_16x16x32_bf16(qf[1], kf1, z, 0,0,0);
      s[ct] = z;
    }

    // static softmax, scale pre-folded into Q: P = exp2(s)
    #pragma unroll
    for(int ct=0;ct<4;ct++){
      #pragma unroll
      for(int j=0;j<4;j++){
        float p = exp2f(s[ct][j]);
        int g = (ct*2 + (fr>>3)) ^ fq;
        Psm[wid][(fq*4 + j)*72 + g*8 + (fr&7)] = f2bfn(p);
      }
    }

    bf16x8 pf[2];
    {
      int key = (fr>>2)&3;
      pf[0] = *(const bf16x8*)(&Psm[wid][fr*72 + ((0*4+fq)^key)*8]);
      pf[1] = *(const bf16x8*)(&Psm[wid][fr*72 + ((1*4+fq)^key)*8]);
    }
    f32x4 o5 = (f32x4){0.f,0.f,0.f,0.f};
    o5 = __builtin_amdgcn_mfma_f32_16x16x32_bf16(pf[0], ones, o5, 0,0,0);
    o5 = __builtin_amdgcn_mfma_f32_16x16x32_bf16(pf[1], ones, o5, 0,0,0);
    #pragma unroll
    for(int j=0;j<4;j++) lrun[j] += o5[j];

    for(int dt=0;dt<4;dt++){
      for(int kc=0;kc<2;kc++){
        bf16x8 vf = *(const bf16x8*)(Vt[cur] + (dt*16 + fr)*72 + kc*32 + fq*8);
        o[dt] = __builtin_amdgcn_mfma_f32_16x16x32_bf16(pf[kc], vf, o[dt], 0,0,0);
      }
    }

    if(kt+1 < 16){
      *(bf16x8*)(Ksm[cur^1] + sr*72 + sc)      = k0r;
      *(bf16x8*)(Ksm[cur^1] + (sr+32)*72 + sc) = k1r;
      *(bf16x8*)(Vt[cur^1]  + sr*72 + sc)      = v0r;
      *(bf16x8*)(Vt[cur^1]  + (sr+32)*72 + sc) = v1r;
    }
    cur ^= 1;
  }

  int b = bh/12, h = bh%12;
  for(int dt=0;dt<4;dt++){
    for(int j=0;j<4;j++){
      int qr = q0 + wid*16 + fq*4 + j;
      float v = o[dt][j] / lrun[j];
      outp[(size_t)(b*1024 + qr)*768 + h*64 + dt*16 + fr] = f2bfn(v);
    }
  }
}

extern "C" void kernel_launch(void* const* d_in, const int* in_sizes, int n_in,
                              void* d_out, int out_size, void* d_ws, size_t ws_size,
                              hipStream_t stream)
{
  const float* x     = (const float*)d_in[0];
  const float* ln1w  = (const float*)d_in[1];
  const float* ln1b  = (const float*)d_in[2];
  const float* qkvw  = (const float*)d_in[3];
  const float* qkvb  = (const float*)d_in[4];
  const float* projw = (const float*)d_in[5];
  const float* projb = (const float*)d_in[6];
  const float* ln2w  = (const float*)d_in[7];
  const float* ln2b  = (const float*)d_in[8];
  const float* fc1w  = (const float*)d_in[9];
  const float* fc1b  = (const float*)d_in[10];
  const float* fc2w  = (const float*)d_in[11];
  const float* fc2b  = (const float*)d_in[12];

  char* ws = (char*)d_ws;
  size_t off = 0;
  auto alloc = [&](size_t bytes){ char* p = ws + off; off += (bytes + 255) & ~255ULL; return p; };
  ushort_t* wq = (ushort_t*)alloc((size_t)2304*768*2);
  ushort_t* wp = (ushort_t*)alloc((size_t)768*768*2);
  ushort_t* w1 = (ushort_t*)alloc((size_t)3072*768*2);
  ushort_t* w2 = (ushort_t*)alloc((size_t)768*3072*2);
  ushort_t* lnbuf  = (ushort_t*)alloc((size_t)8192*768*2);
  ushort_t* qkvbuf = (ushort_t*)alloc((size_t)3*96*1024*64*2);
  ushort_t* attno  = (ushort_t*)alloc((size_t)8192*768*2);
  ushort_t* hbuf   = qkvbuf;   // overlay: fc1 output reuses qkvbuf+attno (both dead)
  float* x1 = (float*)d_out;   // x1 lives in d_out (fp32)

  cvt_all<<<6912, 256, 0, stream>>>(qkvw, projw, fc1w, fc2w, wq, wp, w1, w2);
  ln_kernel<<<8192, 192, 0, stream>>>(x, ln1w, ln1b, lnbuf);
  qkv_gemm8<<<288, 512, 0, stream>>>(lnbuf, wq, qkvb, qkvbuf, 768, 2304, 9);
  attn_kernel<<<dim3(16,96), 256, 0, stream>>>(qkvbuf, attno);
  proj_gemm<<<768, 256, 0, stream>>>(attno, wp, projb, x, x1, 768, 6);
  ln_kernel<<<8192, 192, 0, stream>>>(x1, ln2w, ln2b, lnbuf);
  fc1_gemm8<<<384, 512, 0, stream>>>(lnbuf, w1, fc1b, hbuf, 768, 3072, 12);
  fc2_gemm<<<768, 256, 0, stream>>>(hbuf, w2, fc2b, x1, (float*)d_out, 3072, 6);
}

// Round 22
// 310.756 us; speedup vs baseline: 1.0272x; 1.0272x over previous
//
#include <hip/hip_runtime.h>
#include <hip/hip_bf16.h>
#include <math.h>

typedef __attribute__((ext_vector_type(8))) short bf16x8;
typedef __attribute__((ext_vector_type(4))) float f32x4;
typedef unsigned short ushort_t;

#define GLOAD(srcp, dstp) __builtin_amdgcn_global_load_lds((const __attribute__((address_space(1))) void*)(srcp), (__attribute__((address_space(3))) void*)(dstp), 16, 0, 0)

// native bf16 convert (RNE)
__device__ inline ushort_t f2bfn(float f){
  union{ __bf16 h; ushort_t u; } c;
  c.h = (__bf16)f;
  return c.u;
}

// ---------------- fp32 -> bf16 convert: ALL four weight mats in one dispatch ----------------
__global__ __launch_bounds__(256) void cvt_all(const float* __restrict__ q, const float* __restrict__ p,
                                               const float* __restrict__ f1, const float* __restrict__ f2w,
                                               ushort_t* __restrict__ dq, ushort_t* __restrict__ dp,
                                               ushort_t* __restrict__ d1, ushort_t* __restrict__ d2){
  int i4 = blockIdx.x*256 + threadIdx.x;
  const float* src; ushort_t* dst; int off;
  if(i4 < 442368){ src=q;  dst=dq; off=i4; }
  else if(i4 < 589824){ src=p;  dst=dp; off=i4-442368; }
  else if(i4 < 1179648){ src=f1; dst=d1; off=i4-589824; }
  else { src=f2w; dst=d2; off=i4-1179648; }
  int i = off*4;
  float4 v = *(const float4*)(src+i);
  ushort4 o; o.x=f2bfn(v.x); o.y=f2bfn(v.y); o.z=f2bfn(v.z); o.w=f2bfn(v.w);
  *(ushort4*)(dst+i) = o;
}

// ---------------- LayerNorm: 192 threads (3 waves), float4 loads, ushort4 stores ----------------
__global__ __launch_bounds__(192) void ln_kernel(const float* __restrict__ x, const float* __restrict__ w,
                                                 const float* __restrict__ b, ushort_t* __restrict__ out){
  int row = blockIdx.x, t = threadIdx.x;
  const float4 v = *(const float4*)(x + (size_t)row*768 + t*4);
  float s  = v.x+v.y+v.z+v.w;
  float s2 = v.x*v.x+v.y*v.y+v.z*v.z+v.w*v.w;
  for(int m=1;m<64;m<<=1){ s += __shfl_xor(s,m,64); s2 += __shfl_xor(s2,m,64); }
  __shared__ float ls[3], ls2[3];
  int wv_ = t>>6;
  if((t&63)==0){ ls[wv_]=s; ls2[wv_]=s2; }
  __syncthreads();
  s = ls[0]+ls[1]+ls[2]; s2 = ls2[0]+ls2[1]+ls2[2];
  float mu = s*(1.f/768.f);
  float var = s2*(1.f/768.f) - mu*mu;
  float rs = rsqrtf(var + 1e-5f);
  float4 wv4 = *(const float4*)(w + t*4);
  float4 bv4 = *(const float4*)(b + t*4);
  ushort4 o;
  o.x = f2bfn((v.x-mu)*rs*wv4.x + bv4.x);
  o.y = f2bfn((v.y-mu)*rs*wv4.y + bv4.y);
  o.z = f2bfn((v.z-mu)*rs*wv4.z + bv4.z);
  o.w = f2bfn((v.w-mu)*rs*wv4.w + bv4.w);
  *(ushort4*)(out + (size_t)row*768 + t*4) = o;
}

// =======================================================================
// 8-phase 256x256 GEMM (T1+T2+T3+T4+T5) — REVERTED to round-20 verified state:
// 128KB LDS / 4 slots, 6 barriers/group, mid/end vmcnt(8) counted waits.
// EPI0: qkv scatter; Q block (bn0<768) pre-scaled by c1=0.125*log2e for attn.
// =======================================================================
template<int EPI>
__device__ __forceinline__
void gemm8_body(const ushort_t* __restrict__ A, const ushort_t* __restrict__ BT,
                const float* __restrict__ bias, void* __restrict__ out,
                int K, int Nout, int nBN)
{
  __shared__ ushort_t lds[65536];
  ushort_t* As = lds;
  ushort_t* Bs = lds + 32768;
  const int tid = threadIdx.x;
  const int lane = tid & 63, wid = tid >> 6;
  const int wm = wid >> 2, wn = wid & 3;
  const int fq = lane >> 4, fr = lane & 15;

  const int nwg = (int)gridDim.x;
  const int bid = (int)blockIdx.x;
  const int wg = (bid & 7)*(nwg>>3) + (bid>>3);
  const int bm0 = (wg / nBN) << 8;
  const int bn0 = (wg % nBN) << 8;

  const int srow0 = tid >> 2;
  const int srow1 = 128 + srow0;
  const int sgc = ((tid & 3) ^ ((srow0 >> 1) & 3)) << 3;

  auto stageA = [&](int slot, int tile, int kh){
    const int k0 = (tile<<6) + (kh<<5);
    GLOAD(A + (size_t)(bm0 + srow0)*K + k0 + sgc, As + slot*8192 + (wid*64)*8);
    GLOAD(A + (size_t)(bm0 + srow1)*K + k0 + sgc, As + slot*8192 + (512 + wid*64)*8);
  };
  auto stageB = [&](int slot, int tile, int kh){
    const int k0 = (tile<<6) + (kh<<5);
    GLOAD(BT + (size_t)(bn0 + srow0)*K + k0 + sgc, Bs + slot*8192 + (wid*64)*8);
    GLOAD(BT + (size_t)(bn0 + srow1)*K + k0 + sgc, Bs + slot*8192 + (512 + wid*64)*8);
  };

  int aoff[8], boff[4];
  #pragma unroll
  for(int m=0;m<8;m++){ int r = wm*128 + m*16 + fr; aoff[m] = r*32 + ((fq ^ ((r>>1)&3))<<3); }
  #pragma unroll
  for(int n=0;n<4;n++){ int r = wn*64  + n*16 + fr; boff[n] = r*32 + ((fq ^ ((r>>1)&3))<<3); }

  f32x4 acc[8][4];
  #pragma unroll
  for(int m=0;m<8;m++)
    #pragma unroll
    for(int n=0;n<4;n++) acc[m][n] = (f32x4){0.f,0.f,0.f,0.f};

  const int NT = K >> 6;
  stageA(0,0,0); stageB(0,0,0);
  stageA(1,0,1); stageB(1,0,1);
  stageA(2,1,0); stageB(2,1,0);
  asm volatile("s_waitcnt vmcnt(4)" ::: "memory");   // tile0 (kh0+kh1) landed
  __builtin_amdgcn_s_barrier();

  for(int g=0; g<NT; ++g){
    const int par = g & 1;
    const int sl0 = par*2, sl1 = par*2 + 1;
    const int osl1 = (par^1)*2 + 1;
    bf16x8 a[8], b0, b1;

    // ---- phase 1: kh0, n{0,1} ----
    #pragma unroll
    for(int m=0;m<8;m++) a[m] = *(const bf16x8*)(As + sl0*8192 + aoff[m]);
    b0 = *(const bf16x8*)(Bs + sl0*8192 + boff[0]);
    b1 = *(const bf16x8*)(Bs + sl0*8192 + boff[1]);
    if(g+1 < NT) stageA(osl1, g+1, 1);
    __builtin_amdgcn_s_barrier();
    asm volatile("s_waitcnt lgkmcnt(0)" ::: "memory");
    __builtin_amdgcn_s_setprio(1);
    #pragma unroll
    for(int m=0;m<8;m++){
      acc[m][0] = __builtin_amdgcn_mfma_f32_16x16x32_bf16(a[m], b0, acc[m][0], 0,0,0);
      acc[m][1] = __builtin_amdgcn_mfma_f32_16x16x32_bf16(a[m], b1, acc[m][1], 0,0,0);
    }
    __builtin_amdgcn_s_setprio(0);
    // (post-P1 barrier removed: P2 reads same read-only slot sl0)

    // ---- phase 2: kh0, n{2,3} ----
    b0 = *(const bf16x8*)(Bs + sl0*8192 + boff[2]);
    b1 = *(const bf16x8*)(Bs + sl0*8192 + boff[3]);
    if(g+1 < NT) stageB(osl1, g+1, 1);
    __builtin_amdgcn_s_barrier();
    asm volatile("s_waitcnt lgkmcnt(0)" ::: "memory");
    __builtin_amdgcn_s_setprio(1);
    #pragma unroll
    for(int m=0;m<8;m++){
      acc[m][2] = __builtin_amdgcn_mfma_f32_16x16x32_bf16(a[m], b0, acc[m][2], 0,0,0);
      acc[m][3] = __builtin_amdgcn_mfma_f32_16x16x32_bf16(a[m], b1, acc[m][3], 0,0,0);
    }
    __builtin_amdgcn_s_setprio(0);
    // mid-group wait: ensure CURRENT tile kh1 (staged 4 phases earlier)
    if(g+1 < NT){ asm volatile("s_waitcnt vmcnt(8)" ::: "memory"); }
    else        { asm volatile("s_waitcnt vmcnt(0)" ::: "memory"); }
    __builtin_amdgcn_s_barrier();

    // ---- phase 3: kh1, n{0,1} ----
    #pragma unroll
    for(int m=0;m<8;m++) a[m] = *(const bf16x8*)(As + sl1*8192 + aoff[m]);
    b0 = *(const bf16x8*)(Bs + sl1*8192 + boff[0]);
    b1 = *(const bf16x8*)(Bs + sl1*8192 + boff[1]);
    if(g+2 < NT) stageA(sl0, g+2, 0);
    __builtin_amdgcn_s_barrier();
    asm volatile("s_waitcnt lgkmcnt(0)" ::: "memory");
    __builtin_amdgcn_s_setprio(1);
    #pragma unroll
    for(int m=0;m<8;m++){
      acc[m][0] = __builtin_amdgcn_mfma_f32_16x16x32_bf16(a[m], b0, acc[m][0], 0,0,0);
      acc[m][1] = __builtin_amdgcn_mfma_f32_16x16x32_bf16(a[m], b1, acc[m][1], 0,0,0);
    }
    __builtin_amdgcn_s_setprio(0);
    // (post-P3 barrier removed: P4 reads same read-only slot sl1)

    // ---- phase 4: kh1, n{2,3} ----
    b0 = *(const bf16x8*)(Bs + sl1*8192 + boff[2]);
    b1 = *(const bf16x8*)(Bs + sl1*8192 + boff[3]);
    if(g+2 < NT) stageB(sl0, g+2, 0);
    __builtin_amdgcn_s_barrier();
    asm volatile("s_waitcnt lgkmcnt(0)" ::: "memory");
    __builtin_amdgcn_s_setprio(1);
    #pragma unroll
    for(int m=0;m<8;m++){
      acc[m][2] = __builtin_amdgcn_mfma_f32_16x16x32_bf16(a[m], b0, acc[m][2], 0,0,0);
      acc[m][3] = __builtin_amdgcn_mfma_f32_16x16x32_bf16(a[m], b1, acc[m][3], 0,0,0);
    }
    __builtin_amdgcn_s_setprio(0);
    // end-group wait: ensure NEXT tile kh0 (staged 6 phases earlier)
    if(g+2 < NT)      { asm volatile("s_waitcnt vmcnt(8)" ::: "memory"); }
    else if(g+1 < NT) { asm volatile("s_waitcnt vmcnt(4)" ::: "memory"); }
    else              { asm volatile("s_waitcnt vmcnt(0)" ::: "memory"); }
    __builtin_amdgcn_s_barrier();
  }

  __syncthreads();
  const float qscale = 0.18033688f;   // 0.125 * log2(e), folded into Q for attn
  const bool isQ = (EPI==0) && (bn0 < 768);
  #pragma unroll
  for(int m=0;m<8;m++){
    #pragma unroll
    for(int n=0;n<4;n++){
      int colL = wn*64 + n*16 + fr;
      float bv = bias[bn0 + colL];
      #pragma unroll
      for(int j=0;j<4;j++){
        int rowL = wm*128 + m*16 + fq*4 + j;
        float v = acc[m][n][j] + bv;
        if constexpr(EPI==2){
          float u = fminf(v*(1.0f + 0.044715f*v*v), 40.f);
          float e = exp2f(2.3020052f*u);
          v = v*e/(1.0f+e);
        }
        if(isQ) v *= qscale;
        lds[rowL*256 + (colL ^ (((rowL>>2)&3)<<4))] = f2bfn(v);
      }
    }
  }
  __syncthreads();
  const bool isV = (EPI==0) && (bn0 >= 1536);
  if(!isV){
    #pragma unroll 4
    for(int p=0;p<16;p++){
      int flat = tid + p*512;
      int row = flat>>5;
      int c8  = flat&31;
      int col = c8*8;
      bf16x8 v8 = *(const bf16x8*)&lds[row*256 + (col ^ (((row>>2)&3)<<4))];
      int rg = bm0 + row;
      if constexpr(EPI==0){
        int colg = bn0 + col;
        int which = colg >= 768 ? 1 : 0;
        int rem = colg - which*768;
        int hh = rem>>6, dh = rem&63;
        int bb = rg>>10, np = rg&1023;
        *(bf16x8*)&((ushort_t*)out)[(((size_t)(which*96 + bb*12 + hh)*1024 + np)<<6) + dh] = v8;
      } else {
        *(bf16x8*)&((ushort_t*)out)[(size_t)rg*(size_t)Nout + bn0 + col] = v8;
      }
    }
  } else {
    #pragma unroll 4
    for(int p=0;p<16;p++){
      int flat = tid + p*512;
      int dL = flat>>5;
      int t8 = (flat&31)*8;
      ushort_t tmp[8];
      #pragma unroll
      for(int i=0;i<8;i++){
        int row = t8 + i;
        tmp[i] = lds[row*256 + (dL ^ (((row>>2)&3)<<4))];
      }
      int dg = bn0 - 1536 + dL;
      int hh = dg>>6, dh = dg&63;
      int tok0 = bm0 + t8;
      int bb = tok0>>10, np = tok0&1023;
      *(bf16x8*)&((ushort_t*)out)[((size_t)(192 + bb*12 + hh)*65536) + dh*1024 + np] = *(bf16x8*)tmp;
    }
  }
}

__global__ __launch_bounds__(512, 2)
void qkv_gemm8(const ushort_t* __restrict__ A, const ushort_t* __restrict__ BT,
               const float* __restrict__ bias, void* __restrict__ out, int K, int Nout, int nBN)
{ gemm8_body<0>(A, BT, bias, out, K, Nout, nBN); }

__global__ __launch_bounds__(512, 2)
void fc1_gemm8(const ushort_t* __restrict__ A, const ushort_t* __restrict__ BT,
               const float* __restrict__ bias, void* __restrict__ out, int K, int Nout, int nBN)
{ gemm8_body<2>(A, BT, bias, out, K, Nout, nBN); }

// ---------------- 64x128 GEMM (EPI1: +resid fp32) for proj / fc2 — UNCHANGED (verified r16) ----------------
__device__ __forceinline__
void gemm_body_epi1(const ushort_t* __restrict__ A, const ushort_t* __restrict__ BT,
                    const float* __restrict__ bias, const float* __restrict__ resid,
                    float* __restrict__ out, int K, int nBN)
{
  __shared__ ushort_t Asm[4][64*32];
  __shared__ ushort_t Bsm[4][128*32];
  const int nwg = (int)gridDim.x;
  const int bid = (int)blockIdx.x;
  const int wg = (bid & 7)*(nwg>>3) + (bid>>3);
  const int bm0 = (wg / nBN) * 64;
  const int bn0 = (wg % nBN) * 128;
  const int tid = threadIdx.x;
  const int lane = tid & 63;
  const int wid = tid >> 6;
  const int wn = wid;
  const int fq = lane>>4, fr = lane&15;

  const int rA = tid>>2;
  const int cAs = ((tid&3) ^ ((rA>>1)&3))<<3;
  const int r0 = wid*32 + (lane>>2);
  const int r1 = r0 + 16;
  const int cBs = ((lane&3) ^ ((r0>>1)&3))<<3;

  f32x4 acc[4][2];
  for(int m=0;m<4;m++) for(int n=0;n<2;n++) acc[m][n] = (f32x4){0.f,0.f,0.f,0.f};

  auto STAGE = [&](int buf, int k0){
    GLOAD(A  + (size_t)(bm0+rA)*K + k0 + cAs, &Asm[buf][wid*512]);
    GLOAD(BT + (size_t)(bn0+r0)*K + k0 + cBs, &Bsm[buf][(wid*2)*512]);
    GLOAD(BT + (size_t)(bn0+r1)*K + k0 + cBs, &Bsm[buf][(wid*2+1)*512]);
  };

  int aoff[4], boff[2];
  #pragma unroll
  for(int m=0;m<4;m++){ int r = m*16 + fr; aoff[m] = r*32 + ((fq ^ ((r>>1)&3))<<3); }
  #pragma unroll
  for(int n=0;n<2;n++){ int r = wn*32 + n*16 + fr; boff[n] = r*32 + ((fq ^ ((r>>1)&3))<<3); }

  const int NT = K>>5;
  STAGE(0, 0);
  STAGE(1, 32);
  STAGE(2, 64);
  asm volatile("s_waitcnt vmcnt(6)" ::: "memory");
  __builtin_amdgcn_s_barrier();

  int cur = 0;
  for(int kt=0; kt<NT; ++kt){
    if(kt+3 < NT) STAGE((cur+3)&3, (kt+3)<<5);
    bf16x8 af[4], bfr[2];
    #pragma unroll
    for(int m=0;m<4;m++)
      af[m] = *(const bf16x8*)(&Asm[cur][aoff[m]]);
    #pragma unroll
    for(int n=0;n<2;n++)
      bfr[n] = *(const bf16x8*)(&Bsm[cur][boff[n]]);
    #pragma unroll
    for(int m=0;m<4;m++)
      #pragma unroll
      for(int n=0;n<2;n++)
        acc[m][n] = __builtin_amdgcn_mfma_f32_16x16x32_bf16(af[m], bfr[n], acc[m][n], 0,0,0);
    if(kt+1 < NT){
      if(kt+3 < NT)      { asm volatile("s_waitcnt vmcnt(6)" ::: "memory"); }
      else if(kt+2 < NT) { asm volatile("s_waitcnt vmcnt(3)" ::: "memory"); }
      else               { asm volatile("s_waitcnt vmcnt(0)" ::: "memory"); }
      __builtin_amdgcn_s_barrier();
    }
    cur = (cur+1)&3;
  }

  for(int m=0;m<4;m++){
    int row0 = bm0 + m*16 + fq*4;
    for(int n=0;n<2;n++){
      int col = bn0 + wn*32 + n*16 + fr;
      float bv = bias[col];
      for(int j=0;j<4;j++){
        int r = row0 + j;
        float v = acc[m][n][j] + bv + resid[(size_t)r*768 + col];
        out[(size_t)r*768 + col] = v;
      }
    }
  }
}

__global__ __launch_bounds__(256)
void proj_gemm(const ushort_t* __restrict__ A, const ushort_t* __restrict__ BT,
               const float* __restrict__ bias, const float* __restrict__ resid,
               float* __restrict__ out, int K, int nBN)
{ gemm_body_epi1(A, BT, bias, resid, out, K, nBN); }

__global__ __launch_bounds__(256)
void fc2_gemm(const ushort_t* __restrict__ A, const ushort_t* __restrict__ BT,
              const float* __restrict__ bias, const float* __restrict__ resid,
              float* __restrict__ out, int K, int nBN)
{ gemm_body_epi1(A, BT, bias, resid, out, K, nBN); }

// ---------------- Flash attention — STATIC softmax; Q pre-scaled by c1 (qkv epilogue) ----------------
__global__ __launch_bounds__(256)
void attn_kernel(const ushort_t* __restrict__ qkv, ushort_t* __restrict__ outp)
{
  __shared__ ushort_t Ksm[2][64*72];
  __shared__ ushort_t Vt[2][64*72];
  __shared__ ushort_t Psm[4][16*72];
  const int bh = blockIdx.y;
  const int q0 = blockIdx.x*64;
  const int tid = threadIdx.x, lane = tid&63, wid = tid>>6;
  const int fq = lane>>4, fr = lane&15;
  const ushort_t* Qb = qkv + ((size_t)bh*1024)*64;
  const ushort_t* Kb = qkv + ((size_t)(96 + bh)*1024)*64;
  const ushort_t* Vb = qkv + ((size_t)(192 + bh))*65536;

  bf16x8 ones;
  #pragma unroll
  for(int i=0;i<8;i++) ones[i] = (short)0x3F80;

  bf16x8 qf[2];
  {
    int qr = q0 + wid*16 + fr;
    qf[0] = *(const bf16x8*)(Qb + (size_t)qr*64 +      fq*8);
    qf[1] = *(const bf16x8*)(Qb + (size_t)qr*64 + 32 + fq*8);
  }
  f32x4 o[4];
  for(int dt=0;dt<4;dt++) o[dt] = (f32x4){0.f,0.f,0.f,0.f};
  float lrun[4];
  for(int j=0;j<4;j++) lrun[j]=0.f;

  const int sr = tid>>3, sc = (tid&7)*8;

  bf16x8 k0r = *(const bf16x8*)(Kb + (size_t)sr*64 + sc);
  bf16x8 k1r = *(const bf16x8*)(Kb + (size_t)(sr+32)*64 + sc);
  bf16x8 v0r = *(const bf16x8*)(Vb + (size_t)sr*1024 + sc);
  bf16x8 v1r = *(const bf16x8*)(Vb + (size_t)(sr+32)*1024 + sc);
  *(bf16x8*)(Ksm[0] + sr*72 + sc)      = k0r;
  *(bf16x8*)(Ksm[0] + (sr+32)*72 + sc) = k1r;
  *(bf16x8*)(Vt[0]  + sr*72 + sc)      = v0r;
  *(bf16x8*)(Vt[0]  + (sr+32)*72 + sc) = v1r;

  int cur = 0;
  for(int kt=0; kt<16; kt++){
    __syncthreads();
    if(kt+1 < 16){
      int kv1 = (kt+1)*64;
      k0r = *(const bf16x8*)(Kb + (size_t)(kv1+sr)*64 + sc);
      k1r = *(const bf16x8*)(Kb + (size_t)(kv1+sr+32)*64 + sc);
      v0r = *(const bf16x8*)(Vb + (size_t)sr*1024 + kv1 + sc);
      v1r = *(const bf16x8*)(Vb + (size_t)(sr+32)*1024 + kv1 + sc);
    }

    f32x4 s[4];
    for(int ct=0;ct<4;ct++){
      bf16x8 kf0 = *(const bf16x8*)(Ksm[cur] + (ct*16 + fr)*72 +      fq*8);
      bf16x8 kf1 = *(const bf16x8*)(Ksm[cur] + (ct*16 + fr)*72 + 32 + fq*8);
      f32x4 z = (f32x4){0.f,0.f,0.f,0.f};
      z = __builtin_amdgcn_mfma_f32_16x16x32_bf16(qf[0], kf0, z, 0,0,0);
      z = __builtin_amdgcn_mfma_f32_16x16x32_bf16(qf[1], kf1, z, 0,0,0);
      s[ct] = z;
    }

    // static softmax, scale pre-folded into Q: P = exp2(s)
    #pragma unroll
    for(int ct=0;ct<4;ct++){
      #pragma unroll
      for(int j=0;j<4;j++){
        float p = exp2f(s[ct][j]);
        int g = (ct*2 + (fr>>3)) ^ fq;
        Psm[wid][(fq*4 + j)*72 + g*8 + (fr&7)] = f2bfn(p);
      }
    }

    bf16x8 pf[2];
    {
      int key = (fr>>2)&3;
      pf[0] = *(const bf16x8*)(&Psm[wid][fr*72 + ((0*4+fq)^key)*8]);
      pf[1] = *(const bf16x8*)(&Psm[wid][fr*72 + ((1*4+fq)^key)*8]);
    }
    f32x4 o5 = (f32x4){0.f,0.f,0.f,0.f};
    o5 = __builtin_amdgcn_mfma_f32_16x16x32_bf16(pf[0], ones, o5, 0,0,0);
    o5 = __builtin_amdgcn_mfma_f32_16x16x32_bf16(pf[1], ones, o5, 0,0,0);
    #pragma unroll
    for(int j=0;j<4;j++) lrun[j] += o5[j];

    for(int dt=0;dt<4;dt++){
      for(int kc=0;kc<2;kc++){
        bf16x8 vf = *(const bf16x8*)(Vt[cur] + (dt*16 + fr)*72 + kc*32 + fq*8);
        o[dt] = __builtin_amdgcn_mfma_f32_16x16x32_bf16(pf[kc], vf, o[dt], 0,0,0);
      }
    }

    if(kt+1 < 16){
      *(bf16x8*)(Ksm[cur^1] + sr*72 + sc)      = k0r;
      *(bf16x8*)(Ksm[cur^1] + (sr+32)*72 + sc) = k1r;
      *(bf16x8*)(Vt[cur^1]  + sr*72 + sc)      = v0r;
      *(bf16x8*)(Vt[cur^1]  + (sr+32)*72 + sc) = v1r;
    }
    cur ^= 1;
  }

  int b = bh/12, h = bh%12;
  for(int dt=0;dt<4;dt++){
    for(int j=0;j<4;j++){
      int qr = q0 + wid*16 + fq*4 + j;
      float v = o[dt][j] / lrun[j];
      outp[(size_t)(b*1024 + qr)*768 + h*64 + dt*16 + fr] = f2bfn(v);
    }
  }
}

extern "C" void kernel_launch(void* const* d_in, const int* in_sizes, int n_in,
                              void* d_out, int out_size, void* d_ws, size_t ws_size,
                              hipStream_t stream)
{
  const float* x     = (const float*)d_in[0];
  const float* ln1w  = (const float*)d_in[1];
  const float* ln1b  = (const float*)d_in[2];
  const float* qkvw  = (const float*)d_in[3];
  const float* qkvb  = (const float*)d_in[4];
  const float* projw = (const float*)d_in[5];
  const float* projb = (const float*)d_in[6];
  const float* ln2w  = (const float*)d_in[7];
  const float* ln2b  = (const float*)d_in[8];
  const float* fc1w  = (const float*)d_in[9];
  const float* fc1b  = (const float*)d_in[10];
  const float* fc2w  = (const float*)d_in[11];
  const float* fc2b  = (const float*)d_in[12];

  char* ws = (char*)d_ws;
  size_t off = 0;
  auto alloc = [&](size_t bytes){ char* p = ws + off; off += (bytes + 255) & ~255ULL; return p; };
  ushort_t* wq = (ushort_t*)alloc((size_t)2304*768*2);
  ushort_t* wp = (ushort_t*)alloc((size_t)768*768*2);
  ushort_t* w1 = (ushort_t*)alloc((size_t)3072*768*2);
  ushort_t* w2 = (ushort_t*)alloc((size_t)768*3072*2);
  ushort_t* lnbuf  = (ushort_t*)alloc((size_t)8192*768*2);
  ushort_t* qkvbuf = (ushort_t*)alloc((size_t)3*96*1024*64*2);
  ushort_t* attno  = (ushort_t*)alloc((size_t)8192*768*2);
  ushort_t* hbuf   = qkvbuf;   // overlay: fc1 output reuses qkvbuf+attno (both dead)
  float* x1 = (float*)d_out;   // x1 lives in d_out (fp32)

  cvt_all<<<6912, 256, 0, stream>>>(qkvw, projw, fc1w, fc2w, wq, wp, w1, w2);
  ln_kernel<<<8192, 192, 0, stream>>>(x, ln1w, ln1b, lnbuf);
  qkv_gemm8<<<288, 512, 0, stream>>>(lnbuf, wq, qkvb, qkvbuf, 768, 2304, 9);
  attn_kernel<<<dim3(16,96), 256, 0, stream>>>(qkvbuf, attno);
  proj_gemm<<<768, 256, 0, stream>>>(attno, wp, projb, x, x1, 768, 6);
  ln_kernel<<<8192, 192, 0, stream>>>(x1, ln2w, ln2b, lnbuf);
  fc1_gemm8<<<384, 512, 0, stream>>>(lnbuf, w1, fc1b, hbuf, 768, 3072, 12);
  fc2_gemm<<<768, 256, 0, stream>>>(hbuf, w2, fc2b, x1, (float*)d_out, 3072, 6);
}

// Round 23
// 303.813 us; speedup vs baseline: 1.0507x; 1.0229x over previous
//
#include <hip/hip_runtime.h>
#include <hip/hip_bf16.h>
#include <math.h>

typedef __attribute__((ext_vector_type(8))) short bf16x8;
typedef __attribute__((ext_vector_type(4))) float f32x4;
typedef unsigned short ushort_t;

#define GLOAD(srcp, dstp) __builtin_amdgcn_global_load_lds((const __attribute__((address_space(1))) void*)(srcp), (__attribute__((address_space(3))) void*)(dstp), 16, 0, 0)

// native bf16 convert (RNE)
__device__ inline ushort_t f2bfn(float f){
  union{ __bf16 h; ushort_t u; } c;
  c.h = (__bf16)f;
  return c.u;
}

// ---------------- fp32 -> bf16 convert: ALL four weight mats in one dispatch ----------------
__global__ __launch_bounds__(256) void cvt_all(const float* __restrict__ q, const float* __restrict__ p,
                                               const float* __restrict__ f1, const float* __restrict__ f2w,
                                               ushort_t* __restrict__ dq, ushort_t* __restrict__ dp,
                                               ushort_t* __restrict__ d1, ushort_t* __restrict__ d2){
  int i4 = blockIdx.x*256 + threadIdx.x;
  const float* src; ushort_t* dst; int off;
  if(i4 < 442368){ src=q;  dst=dq; off=i4; }
  else if(i4 < 589824){ src=p;  dst=dp; off=i4-442368; }
  else if(i4 < 1179648){ src=f1; dst=d1; off=i4-589824; }
  else { src=f2w; dst=d2; off=i4-1179648; }
  int i = off*4;
  float4 v = *(const float4*)(src+i);
  ushort4 o; o.x=f2bfn(v.x); o.y=f2bfn(v.y); o.z=f2bfn(v.z); o.w=f2bfn(v.w);
  *(ushort4*)(dst+i) = o;
}

// ---------------- LayerNorm: 192 threads (3 waves), float4 loads, ushort4 stores ----------------
__global__ __launch_bounds__(192) void ln_kernel(const float* __restrict__ x, const float* __restrict__ w,
                                                 const float* __restrict__ b, ushort_t* __restrict__ out){
  int row = blockIdx.x, t = threadIdx.x;
  const float4 v = *(const float4*)(x + (size_t)row*768 + t*4);
  float s  = v.x+v.y+v.z+v.w;
  float s2 = v.x*v.x+v.y*v.y+v.z*v.z+v.w*v.w;
  for(int m=1;m<64;m<<=1){ s += __shfl_xor(s,m,64); s2 += __shfl_xor(s2,m,64); }
  __shared__ float ls[3], ls2[3];
  int wv_ = t>>6;
  if((t&63)==0){ ls[wv_]=s; ls2[wv_]=s2; }
  __syncthreads();
  s = ls[0]+ls[1]+ls[2]; s2 = ls2[0]+ls2[1]+ls2[2];
  float mu = s*(1.f/768.f);
  float var = s2*(1.f/768.f) - mu*mu;
  float rs = rsqrtf(var + 1e-5f);
  float4 wv4 = *(const float4*)(w + t*4);
  float4 bv4 = *(const float4*)(b + t*4);
  ushort4 o;
  o.x = f2bfn((v.x-mu)*rs*wv4.x + bv4.x);
  o.y = f2bfn((v.y-mu)*rs*wv4.y + bv4.y);
  o.z = f2bfn((v.z-mu)*rs*wv4.z + bv4.z);
  o.w = f2bfn((v.w-mu)*rs*wv4.w + bv4.w);
  *(ushort4*)(out + (size_t)row*768 + t*4) = o;
}

// =======================================================================
// 8-phase 256x256 GEMM — FROZEN at round-20/22 verified state.
// =======================================================================
template<int EPI>
__device__ __forceinline__
void gemm8_body(const ushort_t* __restrict__ A, const ushort_t* __restrict__ BT,
                const float* __restrict__ bias, void* __restrict__ out,
                int K, int Nout, int nBN)
{
  __shared__ ushort_t lds[65536];
  ushort_t* As = lds;
  ushort_t* Bs = lds + 32768;
  const int tid = threadIdx.x;
  const int lane = tid & 63, wid = tid >> 6;
  const int wm = wid >> 2, wn = wid & 3;
  const int fq = lane >> 4, fr = lane & 15;

  const int nwg = (int)gridDim.x;
  const int bid = (int)blockIdx.x;
  const int wg = (bid & 7)*(nwg>>3) + (bid>>3);
  const int bm0 = (wg / nBN) << 8;
  const int bn0 = (wg % nBN) << 8;

  const int srow0 = tid >> 2;
  const int srow1 = 128 + srow0;
  const int sgc = ((tid & 3) ^ ((srow0 >> 1) & 3)) << 3;

  auto stageA = [&](int slot, int tile, int kh){
    const int k0 = (tile<<6) + (kh<<5);
    GLOAD(A + (size_t)(bm0 + srow0)*K + k0 + sgc, As + slot*8192 + (wid*64)*8);
    GLOAD(A + (size_t)(bm0 + srow1)*K + k0 + sgc, As + slot*8192 + (512 + wid*64)*8);
  };
  auto stageB = [&](int slot, int tile, int kh){
    const int k0 = (tile<<6) + (kh<<5);
    GLOAD(BT + (size_t)(bn0 + srow0)*K + k0 + sgc, Bs + slot*8192 + (wid*64)*8);
    GLOAD(BT + (size_t)(bn0 + srow1)*K + k0 + sgc, Bs + slot*8192 + (512 + wid*64)*8);
  };

  int aoff[8], boff[4];
  #pragma unroll
  for(int m=0;m<8;m++){ int r = wm*128 + m*16 + fr; aoff[m] = r*32 + ((fq ^ ((r>>1)&3))<<3); }
  #pragma unroll
  for(int n=0;n<4;n++){ int r = wn*64  + n*16 + fr; boff[n] = r*32 + ((fq ^ ((r>>1)&3))<<3); }

  f32x4 acc[8][4];
  #pragma unroll
  for(int m=0;m<8;m++)
    #pragma unroll
    for(int n=0;n<4;n++) acc[m][n] = (f32x4){0.f,0.f,0.f,0.f};

  const int NT = K >> 6;
  stageA(0,0,0); stageB(0,0,0);
  stageA(1,0,1); stageB(1,0,1);
  stageA(2,1,0); stageB(2,1,0);
  asm volatile("s_waitcnt vmcnt(4)" ::: "memory");
  __builtin_amdgcn_s_barrier();

  for(int g=0; g<NT; ++g){
    const int par = g & 1;
    const int sl0 = par*2, sl1 = par*2 + 1;
    const int osl1 = (par^1)*2 + 1;
    bf16x8 a[8], b0, b1;

    #pragma unroll
    for(int m=0;m<8;m++) a[m] = *(const bf16x8*)(As + sl0*8192 + aoff[m]);
    b0 = *(const bf16x8*)(Bs + sl0*8192 + boff[0]);
    b1 = *(const bf16x8*)(Bs + sl0*8192 + boff[1]);
    if(g+1 < NT) stageA(osl1, g+1, 1);
    __builtin_amdgcn_s_barrier();
    asm volatile("s_waitcnt lgkmcnt(0)" ::: "memory");
    __builtin_amdgcn_s_setprio(1);
    #pragma unroll
    for(int m=0;m<8;m++){
      acc[m][0] = __builtin_amdgcn_mfma_f32_16x16x32_bf16(a[m], b0, acc[m][0], 0,0,0);
      acc[m][1] = __builtin_amdgcn_mfma_f32_16x16x32_bf16(a[m], b1, acc[m][1], 0,0,0);
    }
    __builtin_amdgcn_s_setprio(0);

    b0 = *(const bf16x8*)(Bs + sl0*8192 + boff[2]);
    b1 = *(const bf16x8*)(Bs + sl0*8192 + boff[3]);
    if(g+1 < NT) stageB(osl1, g+1, 1);
    __builtin_amdgcn_s_barrier();
    asm volatile("s_waitcnt lgkmcnt(0)" ::: "memory");
    __builtin_amdgcn_s_setprio(1);
    #pragma unroll
    for(int m=0;m<8;m++){
      acc[m][2] = __builtin_amdgcn_mfma_f32_16x16x32_bf16(a[m], b0, acc[m][2], 0,0,0);
      acc[m][3] = __builtin_amdgcn_mfma_f32_16x16x32_bf16(a[m], b1, acc[m][3], 0,0,0);
    }
    __builtin_amdgcn_s_setprio(0);
    if(g+1 < NT){ asm volatile("s_waitcnt vmcnt(8)" ::: "memory"); }
    else        { asm volatile("s_waitcnt vmcnt(0)" ::: "memory"); }
    __builtin_amdgcn_s_barrier();

    #pragma unroll
    for(int m=0;m<8;m++) a[m] = *(const bf16x8*)(As + sl1*8192 + aoff[m]);
    b0 = *(const bf16x8*)(Bs + sl1*8192 + boff[0]);
    b1 = *(const bf16x8*)(Bs + sl1*8192 + boff[1]);
    if(g+2 < NT) stageA(sl0, g+2, 0);
    __builtin_amdgcn_s_barrier();
    asm volatile("s_waitcnt lgkmcnt(0)" ::: "memory");
    __builtin_amdgcn_s_setprio(1);
    #pragma unroll
    for(int m=0;m<8;m++){
      acc[m][0] = __builtin_amdgcn_mfma_f32_16x16x32_bf16(a[m], b0, acc[m][0], 0,0,0);
      acc[m][1] = __builtin_amdgcn_mfma_f32_16x16x32_bf16(a[m], b1, acc[m][1], 0,0,0);
    }
    __builtin_amdgcn_s_setprio(0);

    b0 = *(const bf16x8*)(Bs + sl1*8192 + boff[2]);
    b1 = *(const bf16x8*)(Bs + sl1*8192 + boff[3]);
    if(g+2 < NT) stageB(sl0, g+2, 0);
    __builtin_amdgcn_s_barrier();
    asm volatile("s_waitcnt lgkmcnt(0)" ::: "memory");
    __builtin_amdgcn_s_setprio(1);
    #pragma unroll
    for(int m=0;m<8;m++){
      acc[m][2] = __builtin_amdgcn_mfma_f32_16x16x32_bf16(a[m], b0, acc[m][2], 0,0,0);
      acc[m][3] = __builtin_amdgcn_mfma_f32_16x16x32_bf16(a[m], b1, acc[m][3], 0,0,0);
    }
    __builtin_amdgcn_s_setprio(0);
    if(g+2 < NT)      { asm volatile("s_waitcnt vmcnt(8)" ::: "memory"); }
    else if(g+1 < NT) { asm volatile("s_waitcnt vmcnt(4)" ::: "memory"); }
    else              { asm volatile("s_waitcnt vmcnt(0)" ::: "memory"); }
    __builtin_amdgcn_s_barrier();
  }

  __syncthreads();
  const float qscale = 0.18033688f;   // 0.125 * log2(e), folded into Q for attn
  const bool isQ = (EPI==0) && (bn0 < 768);
  #pragma unroll
  for(int m=0;m<8;m++){
    #pragma unroll
    for(int n=0;n<4;n++){
      int colL = wn*64 + n*16 + fr;
      float bv = bias[bn0 + colL];
      #pragma unroll
      for(int j=0;j<4;j++){
        int rowL = wm*128 + m*16 + fq*4 + j;
        float v = acc[m][n][j] + bv;
        if constexpr(EPI==2){
          float u = fminf(v*(1.0f + 0.044715f*v*v), 40.f);
          float e = exp2f(2.3020052f*u);
          v = v*e/(1.0f+e);
        }
        if(isQ) v *= qscale;
        lds[rowL*256 + (colL ^ (((rowL>>2)&3)<<4))] = f2bfn(v);
      }
    }
  }
  __syncthreads();
  const bool isV = (EPI==0) && (bn0 >= 1536);
  if(!isV){
    #pragma unroll 4
    for(int p=0;p<16;p++){
      int flat = tid + p*512;
      int row = flat>>5;
      int c8  = flat&31;
      int col = c8*8;
      bf16x8 v8 = *(const bf16x8*)&lds[row*256 + (col ^ (((row>>2)&3)<<4))];
      int rg = bm0 + row;
      if constexpr(EPI==0){
        int colg = bn0 + col;
        int which = colg >= 768 ? 1 : 0;
        int rem = colg - which*768;
        int hh = rem>>6, dh = rem&63;
        int bb = rg>>10, np = rg&1023;
        *(bf16x8*)&((ushort_t*)out)[(((size_t)(which*96 + bb*12 + hh)*1024 + np)<<6) + dh] = v8;
      } else {
        *(bf16x8*)&((ushort_t*)out)[(size_t)rg*(size_t)Nout + bn0 + col] = v8;
      }
    }
  } else {
    #pragma unroll 4
    for(int p=0;p<16;p++){
      int flat = tid + p*512;
      int dL = flat>>5;
      int t8 = (flat&31)*8;
      ushort_t tmp[8];
      #pragma unroll
      for(int i=0;i<8;i++){
        int row = t8 + i;
        tmp[i] = lds[row*256 + (dL ^ (((row>>2)&3)<<4))];
      }
      int dg = bn0 - 1536 + dL;
      int hh = dg>>6, dh = dg&63;
      int tok0 = bm0 + t8;
      int bb = tok0>>10, np = tok0&1023;
      *(bf16x8*)&((ushort_t*)out)[((size_t)(192 + bb*12 + hh)*65536) + dh*1024 + np] = *(bf16x8*)tmp;
    }
  }
}

__global__ __launch_bounds__(512, 2)
void qkv_gemm8(const ushort_t* __restrict__ A, const ushort_t* __restrict__ BT,
               const float* __restrict__ bias, void* __restrict__ out, int K, int Nout, int nBN)
{ gemm8_body<0>(A, BT, bias, out, K, Nout, nBN); }

__global__ __launch_bounds__(512, 2)
void fc1_gemm8(const ushort_t* __restrict__ A, const ushort_t* __restrict__ BT,
               const float* __restrict__ bias, void* __restrict__ out, int K, int Nout, int nBN)
{ gemm8_body<2>(A, BT, bias, out, K, Nout, nBN); }

// ---------------- 64x128 GEMM (EPI1: +resid fp32) for proj / fc2 — FROZEN (verified r16) ----------------
__device__ __forceinline__
void gemm_body_epi1(const ushort_t* __restrict__ A, const ushort_t* __restrict__ BT,
                    const float* __restrict__ bias, const float* __restrict__ resid,
                    float* __restrict__ out, int K, int nBN)
{
  __shared__ ushort_t Asm[4][64*32];
  __shared__ ushort_t Bsm[4][128*32];
  const int nwg = (int)gridDim.x;
  const int bid = (int)blockIdx.x;
  const int wg = (bid & 7)*(nwg>>3) + (bid>>3);
  const int bm0 = (wg / nBN) * 64;
  const int bn0 = (wg % nBN) * 128;
  const int tid = threadIdx.x;
  const int lane = tid & 63;
  const int wid = tid >> 6;
  const int wn = wid;
  const int fq = lane>>4, fr = lane&15;

  const int rA = tid>>2;
  const int cAs = ((tid&3) ^ ((rA>>1)&3))<<3;
  const int r0 = wid*32 + (lane>>2);
  const int r1 = r0 + 16;
  const int cBs = ((lane&3) ^ ((r0>>1)&3))<<3;

  f32x4 acc[4][2];
  for(int m=0;m<4;m++) for(int n=0;n<2;n++) acc[m][n] = (f32x4){0.f,0.f,0.f,0.f};

  auto STAGE = [&](int buf, int k0){
    GLOAD(A  + (size_t)(bm0+rA)*K + k0 + cAs, &Asm[buf][wid*512]);
    GLOAD(BT + (size_t)(bn0+r0)*K + k0 + cBs, &Bsm[buf][(wid*2)*512]);
    GLOAD(BT + (size_t)(bn0+r1)*K + k0 + cBs, &Bsm[buf][(wid*2+1)*512]);
  };

  int aoff[4], boff[2];
  #pragma unroll
  for(int m=0;m<4;m++){ int r = m*16 + fr; aoff[m] = r*32 + ((fq ^ ((r>>1)&3))<<3); }
  #pragma unroll
  for(int n=0;n<2;n++){ int r = wn*32 + n*16 + fr; boff[n] = r*32 + ((fq ^ ((r>>1)&3))<<3); }

  const int NT = K>>5;
  STAGE(0, 0);
  STAGE(1, 32);
  STAGE(2, 64);
  asm volatile("s_waitcnt vmcnt(6)" ::: "memory");
  __builtin_amdgcn_s_barrier();

  int cur = 0;
  for(int kt=0; kt<NT; ++kt){
    if(kt+3 < NT) STAGE((cur+3)&3, (kt+3)<<5);
    bf16x8 af[4], bfr[2];
    #pragma unroll
    for(int m=0;m<4;m++)
      af[m] = *(const bf16x8*)(&Asm[cur][aoff[m]]);
    #pragma unroll
    for(int n=0;n<2;n++)
      bfr[n] = *(const bf16x8*)(&Bsm[cur][boff[n]]);
    #pragma unroll
    for(int m=0;m<4;m++)
      #pragma unroll
      for(int n=0;n<2;n++)
        acc[m][n] = __builtin_amdgcn_mfma_f32_16x16x32_bf16(af[m], bfr[n], acc[m][n], 0,0,0);
    if(kt+1 < NT){
      if(kt+3 < NT)      { asm volatile("s_waitcnt vmcnt(6)" ::: "memory"); }
      else if(kt+2 < NT) { asm volatile("s_waitcnt vmcnt(3)" ::: "memory"); }
      else               { asm volatile("s_waitcnt vmcnt(0)" ::: "memory"); }
      __builtin_amdgcn_s_barrier();
    }
    cur = (cur+1)&3;
  }

  for(int m=0;m<4;m++){
    int row0 = bm0 + m*16 + fq*4;
    for(int n=0;n<2;n++){
      int col = bn0 + wn*32 + n*16 + fr;
      float bv = bias[col];
      for(int j=0;j<4;j++){
        int r = row0 + j;
        float v = acc[m][n][j] + bv + resid[(size_t)r*768 + col];
        out[(size_t)r*768 + col] = v;
      }
    }
  }
}

__global__ __launch_bounds__(256)
void proj_gemm(const ushort_t* __restrict__ A, const ushort_t* __restrict__ BT,
               const float* __restrict__ bias, const float* __restrict__ resid,
               float* __restrict__ out, int K, int nBN)
{ gemm_body_epi1(A, BT, bias, resid, out, K, nBN); }

__global__ __launch_bounds__(256)
void fc2_gemm(const ushort_t* __restrict__ A, const ushort_t* __restrict__ BT,
              const float* __restrict__ bias, const float* __restrict__ resid,
              float* __restrict__ out, int K, int nBN)
{ gemm_body_epi1(A, BT, bias, resid, out, K, nBN); }

// ---------------- Flash attention — STATIC softmax; Q pre-scaled.
// ROUND-23: pad-free stride-64 LDS tiles with XOR swizzles:
//   K/V: key = row&7 (rows r and r+32 share key; write granule tid&7, read granules kc*4+fq) — b128 floor.
//   Psm: key = ((row>>2)&3)<<1 (write row=fq*4+j -> key=fq*2; read row=fr) — 8 distinct slots, conflict-free.
// LDS 46080 -> 40960 B => 4 blocks/CU (was 3).
__global__ __launch_bounds__(256)
void attn_kernel(const ushort_t* __restrict__ qkv, ushort_t* __restrict__ outp)
{
  __shared__ ushort_t Ksm[2][64*64];
  __shared__ ushort_t Vt[2][64*64];
  __shared__ ushort_t Psm[4][16*64];
  const int bh = blockIdx.y;
  const int q0 = blockIdx.x*64;
  const int tid = threadIdx.x, lane = tid&63, wid = tid>>6;
  const int fq = lane>>4, fr = lane&15;
  const ushort_t* Qb = qkv + ((size_t)bh*1024)*64;
  const ushort_t* Kb = qkv + ((size_t)(96 + bh)*1024)*64;
  const ushort_t* Vb = qkv + ((size_t)(192 + bh))*65536;

  bf16x8 ones;
  #pragma unroll
  for(int i=0;i<8;i++) ones[i] = (short)0x3F80;

  bf16x8 qf[2];
  {
    int qr = q0 + wid*16 + fr;
    qf[0] = *(const bf16x8*)(Qb + (size_t)qr*64 +      fq*8);
    qf[1] = *(const bf16x8*)(Qb + (size_t)qr*64 + 32 + fq*8);
  }
  f32x4 o[4];
  for(int dt=0;dt<4;dt++) o[dt] = (f32x4){0.f,0.f,0.f,0.f};
  float lrun[4];
  for(int j=0;j<4;j++) lrun[j]=0.f;

  const int sr = tid>>3, sg = tid&7;
  const int sc = sg*8;                          // linear global col
  const int swc = ((sg ^ (sr&7))<<3);           // swizzled LDS col (rows sr, sr+32 share key)

  bf16x8 k0r = *(const bf16x8*)(Kb + (size_t)sr*64 + sc);
  bf16x8 k1r = *(const bf16x8*)(Kb + (size_t)(sr+32)*64 + sc);
  bf16x8 v0r = *(const bf16x8*)(Vb + (size_t)sr*1024 + sc);
  bf16x8 v1r = *(const bf16x8*)(Vb + (size_t)(sr+32)*1024 + sc);
  *(bf16x8*)(Ksm[0] + sr*64 + swc)      = k0r;
  *(bf16x8*)(Ksm[0] + (sr+32)*64 + swc) = k1r;
  *(bf16x8*)(Vt[0]  + sr*64 + swc)      = v0r;
  *(bf16x8*)(Vt[0]  + (sr+32)*64 + swc) = v1r;

  int cur = 0;
  for(int kt=0; kt<16; kt++){
    __syncthreads();
    if(kt+1 < 16){
      int kv1 = (kt+1)*64;
      k0r = *(const bf16x8*)(Kb + (size_t)(kv1+sr)*64 + sc);
      k1r = *(const bf16x8*)(Kb + (size_t)(kv1+sr+32)*64 + sc);
      v0r = *(const bf16x8*)(Vb + (size_t)sr*1024 + kv1 + sc);
      v1r = *(const bf16x8*)(Vb + (size_t)(sr+32)*1024 + kv1 + sc);
    }

    f32x4 s[4];
    for(int ct=0;ct<4;ct++){
      int krow = ct*16 + fr;
      bf16x8 kf0 = *(const bf16x8*)(Ksm[cur] + krow*64 + (((fq  ) ^ (fr&7))<<3));
      bf16x8 kf1 = *(const bf16x8*)(Ksm[cur] + krow*64 + (((4+fq) ^ (fr&7))<<3));
      f32x4 z = (f32x4){0.f,0.f,0.f,0.f};
      z = __builtin_amdgcn_mfma_f32_16x16x32_bf16(qf[0], kf0, z, 0,0,0);
      z = __builtin_amdgcn_mfma_f32_16x16x32_bf16(qf[1], kf1, z, 0,0,0);
      s[ct] = z;
    }

    // static softmax, scale pre-folded into Q: P = exp2(s)
    #pragma unroll
    for(int ct=0;ct<4;ct++){
      #pragma unroll
      for(int j=0;j<4;j++){
        float p = exp2f(s[ct][j]);
        int g = (ct*2 + (fr>>3)) ^ (fq<<1);   // row = fq*4+j -> key = (row>>2)<<1 = fq<<1
        Psm[wid][(fq*4 + j)*64 + g*8 + (fr&7)] = f2bfn(p);
      }
    }

    bf16x8 pf[2];
    {
      int key = ((fr>>2)&3)<<1;               // read row = fr
      pf[0] = *(const bf16x8*)(&Psm[wid][fr*64 + (((0*4+fq)^key)<<3)]);
      pf[1] = *(const bf16x8*)(&Psm[wid][fr*64 + (((1*4+fq)^key)<<3)]);
    }
    f32x4 o5 = (f32x4){0.f,0.f,0.f,0.f};
    o5 = __builtin_amdgcn_mfma_f32_16x16x32_bf16(pf[0], ones, o5, 0,0,0);
    o5 = __builtin_amdgcn_mfma_f32_16x16x32_bf16(pf[1], ones, o5, 0,0,0);
    #pragma unroll
    for(int j=0;j<4;j++) lrun[j] += o5[j];

    for(int dt=0;dt<4;dt++){
      int vrow = dt*16 + fr;
      for(int kc=0;kc<2;kc++){
        bf16x8 vf = *(const bf16x8*)(Vt[cur] + vrow*64 + (((kc*4+fq) ^ (fr&7))<<3));
        o[dt] = __builtin_amdgcn_mfma_f32_16x16x32_bf16(pf[kc], vf, o[dt], 0,0,0);
      }
    }

    if(kt+1 < 16){
      *(bf16x8*)(Ksm[cur^1] + sr*64 + swc)      = k0r;
      *(bf16x8*)(Ksm[cur^1] + (sr+32)*64 + swc) = k1r;
      *(bf16x8*)(Vt[cur^1]  + sr*64 + swc)      = v0r;
      *(bf16x8*)(Vt[cur^1]  + (sr+32)*64 + swc) = v1r;
    }
    cur ^= 1;
  }

  int b = bh/12, h = bh%12;
  for(int dt=0;dt<4;dt++){
    for(int j=0;j<4;j++){
      int qr = q0 + wid*16 + fq*4 + j;
      float v = o[dt][j] / lrun[j];
      outp[(size_t)(b*1024 + qr)*768 + h*64 + dt*16 + fr] = f2bfn(v);
    }
  }
}

extern "C" void kernel_launch(void* const* d_in, const int* in_sizes, int n_in,
                              void* d_out, int out_size, void* d_ws, size_t ws_size,
                              hipStream_t stream)
{
  const float* x     = (const float*)d_in[0];
  const float* ln1w  = (const float*)d_in[1];
  const float* ln1b  = (const float*)d_in[2];
  const float* qkvw  = (const float*)d_in[3];
  const float* qkvb  = (const float*)d_in[4];
  const float* projw = (const float*)d_in[5];
  const float* projb = (const float*)d_in[6];
  const float* ln2w  = (const float*)d_in[7];
  const float* ln2b  = (const float*)d_in[8];
  const float* fc1w  = (const float*)d_in[9];
  const float* fc1b  = (const float*)d_in[10];
  const float* fc2w  = (const float*)d_in[11];
  const float* fc2b  = (const float*)d_in[12];

  char* ws = (char*)d_ws;
  size_t off = 0;
  auto alloc = [&](size_t bytes){ char* p = ws + off; off += (bytes + 255) & ~255ULL; return p; };
  ushort_t* wq = (ushort_t*)alloc((size_t)2304*768*2);
  ushort_t* wp = (ushort_t*)alloc((size_t)768*768*2);
  ushort_t* w1 = (ushort_t*)alloc((size_t)3072*768*2);
  ushort_t* w2 = (ushort_t*)alloc((size_t)768*3072*2);
  ushort_t* lnbuf  = (ushort_t*)alloc((size_t)8192*768*2);
  ushort_t* qkvbuf = (ushort_t*)alloc((size_t)3*96*1024*64*2);
  ushort_t* attno  = (ushort_t*)alloc((size_t)8192*768*2);
  ushort_t* hbuf   = qkvbuf;   // overlay: fc1 output reuses qkvbuf+attno (both dead)
  float* x1 = (float*)d_out;   // x1 lives in d_out (fp32)

  cvt_all<<<6912, 256, 0, stream>>>(qkvw, projw, fc1w, fc2w, wq, wp, w1, w2);
  ln_kernel<<<8192, 192, 0, stream>>>(x, ln1w, ln1b, lnbuf);
  qkv_gemm8<<<288, 512, 0, stream>>>(lnbuf, wq, qkvb, qkvbuf, 768, 2304, 9);
  attn_kernel<<<dim3(16,96), 256, 0, stream>>>(qkvbuf, attno);
  proj_gemm<<<768, 256, 0, stream>>>(attno, wp, projb, x, x1, 768, 6);
  ln_kernel<<<8192, 192, 0, stream>>>(x1, ln2w, ln2b, lnbuf);
  fc1_gemm8<<<384, 512, 0, stream>>>(lnbuf, w1, fc1b, hbuf, 768, 3072, 12);
  fc2_gemm<<<768, 256, 0, stream>>>(hbuf, w2, fc2b, x1, (float*)d_out, 3072, 6);
}

// Round 24
// 303.004 us; speedup vs baseline: 1.0535x; 1.0027x over previous
//
#include <hip/hip_runtime.h>
#include <hip/hip_bf16.h>
#include <math.h>

typedef __attribute__((ext_vector_type(8))) short bf16x8;
typedef __attribute__((ext_vector_type(4))) float f32x4;
typedef unsigned short ushort_t;

#define GLOAD(srcp, dstp) __builtin_amdgcn_global_load_lds((const __attribute__((address_space(1))) void*)(srcp), (__attribute__((address_space(3))) void*)(dstp), 16, 0, 0)

// native bf16 convert (RNE)
__device__ inline ushort_t f2bfn(float f){
  union{ __bf16 h; ushort_t u; } c;
  c.h = (__bf16)f;
  return c.u;
}

// ---------------- merged: weight cvt (blocks 0..6911) + LN1 (blocks 6912..15103) ----------------
// Independent work co-scheduled in one dispatch (same-stream kernels cannot overlap).
__global__ __launch_bounds__(256) void cvt_ln(const float* __restrict__ q, const float* __restrict__ p,
                                              const float* __restrict__ f1, const float* __restrict__ f2w,
                                              ushort_t* __restrict__ dq, ushort_t* __restrict__ dp,
                                              ushort_t* __restrict__ d1, ushort_t* __restrict__ d2,
                                              const float* __restrict__ x, const float* __restrict__ lw,
                                              const float* __restrict__ lb, ushort_t* __restrict__ lout){
  int bid = blockIdx.x;
  if(bid < 6912){
    int i4 = bid*256 + threadIdx.x;
    const float* src; ushort_t* dst; int off;
    if(i4 < 442368){ src=q;  dst=dq; off=i4; }
    else if(i4 < 589824){ src=p;  dst=dp; off=i4-442368; }
    else if(i4 < 1179648){ src=f1; dst=d1; off=i4-589824; }
    else { src=f2w; dst=d2; off=i4-1179648; }
    int i = off*4;
    float4 v = *(const float4*)(src+i);
    ushort4 o; o.x=f2bfn(v.x); o.y=f2bfn(v.y); o.z=f2bfn(v.z); o.w=f2bfn(v.w);
    *(ushort4*)(dst+i) = o;
  } else {
    int row = bid - 6912, t = threadIdx.x;
    __shared__ float ls[4], ls2[4];
    float4 v = (float4){0.f,0.f,0.f,0.f};
    float s = 0.f, s2 = 0.f;
    if(t < 192){
      v = *(const float4*)(x + (size_t)row*768 + t*4);
      s  = v.x+v.y+v.z+v.w;
      s2 = v.x*v.x+v.y*v.y+v.z*v.z+v.w*v.w;
    }
    for(int m=1;m<64;m<<=1){ s += __shfl_xor(s,m,64); s2 += __shfl_xor(s2,m,64); }
    int wv_ = t>>6;
    if((t&63)==0){ ls[wv_]=s; ls2[wv_]=s2; }   // wave 3 writes zeros (harmless)
    __syncthreads();
    s = ls[0]+ls[1]+ls[2]+ls[3]; s2 = ls2[0]+ls2[1]+ls2[2]+ls2[3];
    float mu = s*(1.f/768.f);
    float var = s2*(1.f/768.f) - mu*mu;
    float rs = rsqrtf(var + 1e-5f);
    if(t < 192){
      float4 wv4 = *(const float4*)(lw + t*4);
      float4 bv4 = *(const float4*)(lb + t*4);
      ushort4 o;
      o.x = f2bfn((v.x-mu)*rs*wv4.x + bv4.x);
      o.y = f2bfn((v.y-mu)*rs*wv4.y + bv4.y);
      o.z = f2bfn((v.z-mu)*rs*wv4.z + bv4.z);
      o.w = f2bfn((v.w-mu)*rs*wv4.w + bv4.w);
      *(ushort4*)(lout + (size_t)row*768 + t*4) = o;
    }
  }
}

// ---------------- LayerNorm (LN2): 192 threads, float4 loads, ushort4 stores ----------------
__global__ __launch_bounds__(192) void ln_kernel(const float* __restrict__ x, const float* __restrict__ w,
                                                 const float* __restrict__ b, ushort_t* __restrict__ out){
  int row = blockIdx.x, t = threadIdx.x;
  const float4 v = *(const float4*)(x + (size_t)row*768 + t*4);
  float s  = v.x+v.y+v.z+v.w;
  float s2 = v.x*v.x+v.y*v.y+v.z*v.z+v.w*v.w;
  for(int m=1;m<64;m<<=1){ s += __shfl_xor(s,m,64); s2 += __shfl_xor(s2,m,64); }
  __shared__ float ls[3], ls2[3];
  int wv_ = t>>6;
  if((t&63)==0){ ls[wv_]=s; ls2[wv_]=s2; }
  __syncthreads();
  s = ls[0]+ls[1]+ls[2]; s2 = ls2[0]+ls2[1]+ls2[2];
  float mu = s*(1.f/768.f);
  float var = s2*(1.f/768.f) - mu*mu;
  float rs = rsqrtf(var + 1e-5f);
  float4 wv4 = *(const float4*)(w + t*4);
  float4 bv4 = *(const float4*)(b + t*4);
  ushort4 o;
  o.x = f2bfn((v.x-mu)*rs*wv4.x + bv4.x);
  o.y = f2bfn((v.y-mu)*rs*wv4.y + bv4.y);
  o.z = f2bfn((v.z-mu)*rs*wv4.z + bv4.z);
  o.w = f2bfn((v.w-mu)*rs*wv4.w + bv4.w);
  *(ushort4*)(out + (size_t)row*768 + t*4) = o;
}

// =======================================================================
// 8-phase 256x256 GEMM — FROZEN at round-20/22 verified state.
// =======================================================================
template<int EPI>
__device__ __forceinline__
void gemm8_body(const ushort_t* __restrict__ A, const ushort_t* __restrict__ BT,
                const float* __restrict__ bias, void* __restrict__ out,
                int K, int Nout, int nBN)
{
  __shared__ ushort_t lds[65536];
  ushort_t* As = lds;
  ushort_t* Bs = lds + 32768;
  const int tid = threadIdx.x;
  const int lane = tid & 63, wid = tid >> 6;
  const int wm = wid >> 2, wn = wid & 3;
  const int fq = lane >> 4, fr = lane & 15;

  const int nwg = (int)gridDim.x;
  const int bid = (int)blockIdx.x;
  const int wg = (bid & 7)*(nwg>>3) + (bid>>3);
  const int bm0 = (wg / nBN) << 8;
  const int bn0 = (wg % nBN) << 8;

  const int srow0 = tid >> 2;
  const int srow1 = 128 + srow0;
  const int sgc = ((tid & 3) ^ ((srow0 >> 1) & 3)) << 3;

  auto stageA = [&](int slot, int tile, int kh){
    const int k0 = (tile<<6) + (kh<<5);
    GLOAD(A + (size_t)(bm0 + srow0)*K + k0 + sgc, As + slot*8192 + (wid*64)*8);
    GLOAD(A + (size_t)(bm0 + srow1)*K + k0 + sgc, As + slot*8192 + (512 + wid*64)*8);
  };
  auto stageB = [&](int slot, int tile, int kh){
    const int k0 = (tile<<6) + (kh<<5);
    GLOAD(BT + (size_t)(bn0 + srow0)*K + k0 + sgc, Bs + slot*8192 + (wid*64)*8);
    GLOAD(BT + (size_t)(bn0 + srow1)*K + k0 + sgc, Bs + slot*8192 + (512 + wid*64)*8);
  };

  int aoff[8], boff[4];
  #pragma unroll
  for(int m=0;m<8;m++){ int r = wm*128 + m*16 + fr; aoff[m] = r*32 + ((fq ^ ((r>>1)&3))<<3); }
  #pragma unroll
  for(int n=0;n<4;n++){ int r = wn*64  + n*16 + fr; boff[n] = r*32 + ((fq ^ ((r>>1)&3))<<3); }

  f32x4 acc[8][4];
  #pragma unroll
  for(int m=0;m<8;m++)
    #pragma unroll
    for(int n=0;n<4;n++) acc[m][n] = (f32x4){0.f,0.f,0.f,0.f};

  const int NT = K >> 6;
  stageA(0,0,0); stageB(0,0,0);
  stageA(1,0,1); stageB(1,0,1);
  stageA(2,1,0); stageB(2,1,0);
  asm volatile("s_waitcnt vmcnt(4)" ::: "memory");
  __builtin_amdgcn_s_barrier();

  for(int g=0; g<NT; ++g){
    const int par = g & 1;
    const int sl0 = par*2, sl1 = par*2 + 1;
    const int osl1 = (par^1)*2 + 1;
    bf16x8 a[8], b0, b1;

    #pragma unroll
    for(int m=0;m<8;m++) a[m] = *(const bf16x8*)(As + sl0*8192 + aoff[m]);
    b0 = *(const bf16x8*)(Bs + sl0*8192 + boff[0]);
    b1 = *(const bf16x8*)(Bs + sl0*8192 + boff[1]);
    if(g+1 < NT) stageA(osl1, g+1, 1);
    __builtin_amdgcn_s_barrier();
    asm volatile("s_waitcnt lgkmcnt(0)" ::: "memory");
    __builtin_amdgcn_s_setprio(1);
    #pragma unroll
    for(int m=0;m<8;m++){
      acc[m][0] = __builtin_amdgcn_mfma_f32_16x16x32_bf16(a[m], b0, acc[m][0], 0,0,0);
      acc[m][1] = __builtin_amdgcn_mfma_f32_16x16x32_bf16(a[m], b1, acc[m][1], 0,0,0);
    }
    __builtin_amdgcn_s_setprio(0);

    b0 = *(const bf16x8*)(Bs + sl0*8192 + boff[2]);
    b1 = *(const bf16x8*)(Bs + sl0*8192 + boff[3]);
    if(g+1 < NT) stageB(osl1, g+1, 1);
    __builtin_amdgcn_s_barrier();
    asm volatile("s_waitcnt lgkmcnt(0)" ::: "memory");
    __builtin_amdgcn_s_setprio(1);
    #pragma unroll
    for(int m=0;m<8;m++){
      acc[m][2] = __builtin_amdgcn_mfma_f32_16x16x32_bf16(a[m], b0, acc[m][2], 0,0,0);
      acc[m][3] = __builtin_amdgcn_mfma_f32_16x16x32_bf16(a[m], b1, acc[m][3], 0,0,0);
    }
    __builtin_amdgcn_s_setprio(0);
    if(g+1 < NT){ asm volatile("s_waitcnt vmcnt(8)" ::: "memory"); }
    else        { asm volatile("s_waitcnt vmcnt(0)" ::: "memory"); }
    __builtin_amdgcn_s_barrier();

    #pragma unroll
    for(int m=0;m<8;m++) a[m] = *(const bf16x8*)(As + sl1*8192 + aoff[m]);
    b0 = *(const bf16x8*)(Bs + sl1*8192 + boff[0]);
    b1 = *(const bf16x8*)(Bs + sl1*8192 + boff[1]);
    if(g+2 < NT) stageA(sl0, g+2, 0);
    __builtin_amdgcn_s_barrier();
    asm volatile("s_waitcnt lgkmcnt(0)" ::: "memory");
    __builtin_amdgcn_s_setprio(1);
    #pragma unroll
    for(int m=0;m<8;m++){
      acc[m][0] = __builtin_amdgcn_mfma_f32_16x16x32_bf16(a[m], b0, acc[m][0], 0,0,0);
      acc[m][1] = __builtin_amdgcn_mfma_f32_16x16x32_bf16(a[m], b1, acc[m][1], 0,0,0);
    }
    __builtin_amdgcn_s_setprio(0);

    b0 = *(const bf16x8*)(Bs + sl1*8192 + boff[2]);
    b1 = *(const bf16x8*)(Bs + sl1*8192 + boff[3]);
    if(g+2 < NT) stageB(sl0, g+2, 0);
    __builtin_amdgcn_s_barrier();
    asm volatile("s_waitcnt lgkmcnt(0)" ::: "memory");
    __builtin_amdgcn_s_setprio(1);
    #pragma unroll
    for(int m=0;m<8;m++){
      acc[m][2] = __builtin_amdgcn_mfma_f32_16x16x32_bf16(a[m], b0, acc[m][2], 0,0,0);
      acc[m][3] = __builtin_amdgcn_mfma_f32_16x16x32_bf16(a[m], b1, acc[m][3], 0,0,0);
    }
    __builtin_amdgcn_s_setprio(0);
    if(g+2 < NT)      { asm volatile("s_waitcnt vmcnt(8)" ::: "memory"); }
    else if(g+1 < NT) { asm volatile("s_waitcnt vmcnt(4)" ::: "memory"); }
    else              { asm volatile("s_waitcnt vmcnt(0)" ::: "memory"); }
    __builtin_amdgcn_s_barrier();
  }

  __syncthreads();
  const float qscale = 0.18033688f;   // 0.125 * log2(e), folded into Q for attn
  const bool isQ = (EPI==0) && (bn0 < 768);
  #pragma unroll
  for(int m=0;m<8;m++){
    #pragma unroll
    for(int n=0;n<4;n++){
      int colL = wn*64 + n*16 + fr;
      float bv = bias[bn0 + colL];
      #pragma unroll
      for(int j=0;j<4;j++){
        int rowL = wm*128 + m*16 + fq*4 + j;
        float v = acc[m][n][j] + bv;
        if constexpr(EPI==2){
          float u = fminf(v*(1.0f + 0.044715f*v*v), 40.f);
          float e = exp2f(2.3020052f*u);
          v = v*e/(1.0f+e);
        }
        if(isQ) v *= qscale;
        lds[rowL*256 + (colL ^ (((rowL>>2)&3)<<4))] = f2bfn(v);
      }
    }
  }
  __syncthreads();
  const bool isV = (EPI==0) && (bn0 >= 1536);
  if(!isV){
    #pragma unroll 4
    for(int p=0;p<16;p++){
      int flat = tid + p*512;
      int row = flat>>5;
      int c8  = flat&31;
      int col = c8*8;
      bf16x8 v8 = *(const bf16x8*)&lds[row*256 + (col ^ (((row>>2)&3)<<4))];
      int rg = bm0 + row;
      if constexpr(EPI==0){
        int colg = bn0 + col;
        int which = colg >= 768 ? 1 : 0;
        int rem = colg - which*768;
        int hh = rem>>6, dh = rem&63;
        int bb = rg>>10, np = rg&1023;
        *(bf16x8*)&((ushort_t*)out)[(((size_t)(which*96 + bb*12 + hh)*1024 + np)<<6) + dh] = v8;
      } else {
        *(bf16x8*)&((ushort_t*)out)[(size_t)rg*(size_t)Nout + bn0 + col] = v8;
      }
    }
  } else {
    #pragma unroll 4
    for(int p=0;p<16;p++){
      int flat = tid + p*512;
      int dL = flat>>5;
      int t8 = (flat&31)*8;
      ushort_t tmp[8];
      #pragma unroll
      for(int i=0;i<8;i++){
        int row = t8 + i;
        tmp[i] = lds[row*256 + (dL ^ (((row>>2)&3)<<4))];
      }
      int dg = bn0 - 1536 + dL;
      int hh = dg>>6, dh = dg&63;
      int tok0 = bm0 + t8;
      int bb = tok0>>10, np = tok0&1023;
      *(bf16x8*)&((ushort_t*)out)[((size_t)(192 + bb*12 + hh)*65536) + dh*1024 + np] = *(bf16x8*)tmp;
    }
  }
}

__global__ __launch_bounds__(512, 2)
void qkv_gemm8(const ushort_t* __restrict__ A, const ushort_t* __restrict__ BT,
               const float* __restrict__ bias, void* __restrict__ out, int K, int Nout, int nBN)
{ gemm8_body<0>(A, BT, bias, out, K, Nout, nBN); }

__global__ __launch_bounds__(512, 2)
void fc1_gemm8(const ushort_t* __restrict__ A, const ushort_t* __restrict__ BT,
               const float* __restrict__ bias, void* __restrict__ out, int K, int Nout, int nBN)
{ gemm8_body<2>(A, BT, bias, out, K, Nout, nBN); }

// ---------------- 64x128 GEMM (EPI1: +resid fp32) for proj / fc2 — FROZEN (verified r16) ----------------
__device__ __forceinline__
void gemm_body_epi1(const ushort_t* __restrict__ A, const ushort_t* __restrict__ BT,
                    const float* __restrict__ bias, const float* __restrict__ resid,
                    float* __restrict__ out, int K, int nBN)
{
  __shared__ ushort_t Asm[4][64*32];
  __shared__ ushort_t Bsm[4][128*32];
  const int nwg = (int)gridDim.x;
  const int bid = (int)blockIdx.x;
  const int wg = (bid & 7)*(nwg>>3) + (bid>>3);
  const int bm0 = (wg / nBN) * 64;
  const int bn0 = (wg % nBN) * 128;
  const int tid = threadIdx.x;
  const int lane = tid & 63;
  const int wid = tid >> 6;
  const int wn = wid;
  const int fq = lane>>4, fr = lane&15;

  const int rA = tid>>2;
  const int cAs = ((tid&3) ^ ((rA>>1)&3))<<3;
  const int r0 = wid*32 + (lane>>2);
  const int r1 = r0 + 16;
  const int cBs = ((lane&3) ^ ((r0>>1)&3))<<3;

  f32x4 acc[4][2];
  for(int m=0;m<4;m++) for(int n=0;n<2;n++) acc[m][n] = (f32x4){0.f,0.f,0.f,0.f};

  auto STAGE = [&](int buf, int k0){
    GLOAD(A  + (size_t)(bm0+rA)*K + k0 + cAs, &Asm[buf][wid*512]);
    GLOAD(BT + (size_t)(bn0+r0)*K + k0 + cBs, &Bsm[buf][(wid*2)*512]);
    GLOAD(BT + (size_t)(bn0+r1)*K + k0 + cBs, &Bsm[buf][(wid*2+1)*512]);
  };

  int aoff[4], boff[2];
  #pragma unroll
  for(int m=0;m<4;m++){ int r = m*16 + fr; aoff[m] = r*32 + ((fq ^ ((r>>1)&3))<<3); }
  #pragma unroll
  for(int n=0;n<2;n++){ int r = wn*32 + n*16 + fr; boff[n] = r*32 + ((fq ^ ((r>>1)&3))<<3); }

  const int NT = K>>5;
  STAGE(0, 0);
  STAGE(1, 32);
  STAGE(2, 64);
  asm volatile("s_waitcnt vmcnt(6)" ::: "memory");
  __builtin_amdgcn_s_barrier();

  int cur = 0;
  for(int kt=0; kt<NT; ++kt){
    if(kt+3 < NT) STAGE((cur+3)&3, (kt+3)<<5);
    bf16x8 af[4], bfr[2];
    #pragma unroll
    for(int m=0;m<4;m++)
      af[m] = *(const bf16x8*)(&Asm[cur][aoff[m]]);
    #pragma unroll
    for(int n=0;n<2;n++)
      bfr[n] = *(const bf16x8*)(&Bsm[cur][boff[n]]);
    #pragma unroll
    for(int m=0;m<4;m++)
      #pragma unroll
      for(int n=0;n<2;n++)
        acc[m][n] = __builtin_amdgcn_mfma_f32_16x16x32_bf16(af[m], bfr[n], acc[m][n], 0,0,0);
    if(kt+1 < NT){
      if(kt+3 < NT)      { asm volatile("s_waitcnt vmcnt(6)" ::: "memory"); }
      else if(kt+2 < NT) { asm volatile("s_waitcnt vmcnt(3)" ::: "memory"); }
      else               { asm volatile("s_waitcnt vmcnt(0)" ::: "memory"); }
      __builtin_amdgcn_s_barrier();
    }
    cur = (cur+1)&3;
  }

  for(int m=0;m<4;m++){
    int row0 = bm0 + m*16 + fq*4;
    for(int n=0;n<2;n++){
      int col = bn0 + wn*32 + n*16 + fr;
      float bv = bias[col];
      for(int j=0;j<4;j++){
        int r = row0 + j;
        float v = acc[m][n][j] + bv + resid[(size_t)r*768 + col];
        out[(size_t)r*768 + col] = v;
      }
    }
  }
}

__global__ __launch_bounds__(256)
void proj_gemm(const ushort_t* __restrict__ A, const ushort_t* __restrict__ BT,
               const float* __restrict__ bias, const float* __restrict__ resid,
               float* __restrict__ out, int K, int nBN)
{ gemm_body_epi1(A, BT, bias, resid, out, K, nBN); }

__global__ __launch_bounds__(256)
void fc2_gemm(const ushort_t* __restrict__ A, const ushort_t* __restrict__ BT,
              const float* __restrict__ bias, const float* __restrict__ resid,
              float* __restrict__ out, int K, int nBN)
{ gemm_body_epi1(A, BT, bias, resid, out, K, nBN); }

// ---------------- Flash attention — FROZEN at round-23 verified state ----------------
__global__ __launch_bounds__(256)
void attn_kernel(const ushort_t* __restrict__ qkv, ushort_t* __restrict__ outp)
{
  __shared__ ushort_t Ksm[2][64*64];
  __shared__ ushort_t Vt[2][64*64];
  __shared__ ushort_t Psm[4][16*64];
  const int bh = blockIdx.y;
  const int q0 = blockIdx.x*64;
  const int tid = threadIdx.x, lane = tid&63, wid = tid>>6;
  const int fq = lane>>4, fr = lane&15;
  const ushort_t* Qb = qkv + ((size_t)bh*1024)*64;
  const ushort_t* Kb = qkv + ((size_t)(96 + bh)*1024)*64;
  const ushort_t* Vb = qkv + ((size_t)(192 + bh))*65536;

  bf16x8 ones;
  #pragma unroll
  for(int i=0;i<8;i++) ones[i] = (short)0x3F80;

  bf16x8 qf[2];
  {
    int qr = q0 + wid*16 + fr;
    qf[0] = *(const bf16x8*)(Qb + (size_t)qr*64 +      fq*8);
    qf[1] = *(const bf16x8*)(Qb + (size_t)qr*64 + 32 + fq*8);
  }
  f32x4 o[4];
  for(int dt=0;dt<4;dt++) o[dt] = (f32x4){0.f,0.f,0.f,0.f};
  float lrun[4];
  for(int j=0;j<4;j++) lrun[j]=0.f;

  const int sr = tid>>3, sg = tid&7;
  const int sc = sg*8;
  const int swc = ((sg ^ (sr&7))<<3);

  bf16x8 k0r = *(const bf16x8*)(Kb + (size_t)sr*64 + sc);
  bf16x8 k1r = *(const bf16x8*)(Kb + (size_t)(sr+32)*64 + sc);
  bf16x8 v0r = *(const bf16x8*)(Vb + (size_t)sr*1024 + sc);
  bf16x8 v1r = *(const bf16x8*)(Vb + (size_t)(sr+32)*1024 + sc);
  *(bf16x8*)(Ksm[0] + sr*64 + swc)      = k0r;
  *(bf16x8*)(Ksm[0] + (sr+32)*64 + swc) = k1r;
  *(bf16x8*)(Vt[0]  + sr*64 + swc)      = v0r;
  *(bf16x8*)(Vt[0]  + (sr+32)*64 + swc) = v1r;

  int cur = 0;
  for(int kt=0; kt<16; kt++){
    __syncthreads();
    if(kt+1 < 16){
      int kv1 = (kt+1)*64;
      k0r = *(const bf16x8*)(Kb + (size_t)(kv1+sr)*64 + sc);
      k1r = *(const bf16x8*)(Kb + (size_t)(kv1+sr+32)*64 + sc);
      v0r = *(const bf16x8*)(Vb + (size_t)sr*1024 + kv1 + sc);
      v1r = *(const bf16x8*)(Vb + (size_t)(sr+32)*1024 + kv1 + sc);
    }

    f32x4 s[4];
    for(int ct=0;ct<4;ct++){
      int krow = ct*16 + fr;
      bf16x8 kf0 = *(const bf16x8*)(Ksm[cur] + krow*64 + (((fq  ) ^ (fr&7))<<3));
      bf16x8 kf1 = *(const bf16x8*)(Ksm[cur] + krow*64 + (((4+fq) ^ (fr&7))<<3));
      f32x4 z = (f32x4){0.f,0.f,0.f,0.f};
      z = __builtin_amdgcn_mfma_f32_16x16x32_bf16(qf[0], kf0, z, 0,0,0);
      z = __builtin_amdgcn_mfma_f32_16x16x32_bf16(qf[1], kf1, z, 0,0,0);
      s[ct] = z;
    }

    #pragma unroll
    for(int ct=0;ct<4;ct++){
      #pragma unroll
      for(int j=0;j<4;j++){
        float p = exp2f(s[ct][j]);
        int g = (ct*2 + (fr>>3)) ^ (fq<<1);
        Psm[wid][(fq*4 + j)*64 + g*8 + (fr&7)] = f2bfn(p);
      }
    }

    bf16x8 pf[2];
    {
      int key = ((fr>>2)&3)<<1;
      pf[0] = *(const bf16x8*)(&Psm[wid][fr*64 + (((0*4+fq)^key)<<3)]);
      pf[1] = *(const bf16x8*)(&Psm[wid][fr*64 + (((1*4+fq)^key)<<3)]);
    }
    f32x4 o5 = (f32x4){0.f,0.f,0.f,0.f};
    o5 = __builtin_amdgcn_mfma_f32_16x16x32_bf16(pf[0], ones, o5, 0,0,0);
    o5 = __builtin_amdgcn_mfma_f32_16x16x32_bf16(pf[1], ones, o5, 0,0,0);
    #pragma unroll
    for(int j=0;j<4;j++) lrun[j] += o5[j];

    for(int dt=0;dt<4;dt++){
      int vrow = dt*16 + fr;
      for(int kc=0;kc<2;kc++){
        bf16x8 vf = *(const bf16x8*)(Vt[cur] + vrow*64 + (((kc*4+fq) ^ (fr&7))<<3));
        o[dt] = __builtin_amdgcn_mfma_f32_16x16x32_bf16(pf[kc], vf, o[dt], 0,0,0);
      }
    }

    if(kt+1 < 16){
      *(bf16x8*)(Ksm[cur^1] + sr*64 + swc)      = k0r;
      *(bf16x8*)(Ksm[cur^1] + (sr+32)*64 + swc) = k1r;
      *(bf16x8*)(Vt[cur^1]  + sr*64 + swc)      = v0r;
      *(bf16x8*)(Vt[cur^1]  + (sr+32)*64 + swc) = v1r;
    }
    cur ^= 1;
  }

  int b = bh/12, h = bh%12;
  for(int dt=0;dt<4;dt++){
    for(int j=0;j<4;j++){
      int qr = q0 + wid*16 + fq*4 + j;
      float v = o[dt][j] / lrun[j];
      outp[(size_t)(b*1024 + qr)*768 + h*64 + dt*16 + fr] = f2bfn(v);
    }
  }
}

extern "C" void kernel_launch(void* const* d_in, const int* in_sizes, int n_in,
                              void* d_out, int out_size, void* d_ws, size_t ws_size,
                              hipStream_t stream)
{
  const float* x     = (const float*)d_in[0];
  const float* ln1w  = (const float*)d_in[1];
  const float* ln1b  = (const float*)d_in[2];
  const float* qkvw  = (const float*)d_in[3];
  const float* qkvb  = (const float*)d_in[4];
  const float* projw = (const float*)d_in[5];
  const float* projb = (const float*)d_in[6];
  const float* ln2w  = (const float*)d_in[7];
  const float* ln2b  = (const float*)d_in[8];
  const float* fc1w  = (const float*)d_in[9];
  const float* fc1b  = (const float*)d_in[10];
  const float* fc2w  = (const float*)d_in[11];
  const float* fc2b  = (const float*)d_in[12];

  char* ws = (char*)d_ws;
  size_t off = 0;
  auto alloc = [&](size_t bytes){ char* p = ws + off; off += (bytes + 255) & ~255ULL; return p; };
  ushort_t* wq = (ushort_t*)alloc((size_t)2304*768*2);
  ushort_t* wp = (ushort_t*)alloc((size_t)768*768*2);
  ushort_t* w1 = (ushort_t*)alloc((size_t)3072*768*2);
  ushort_t* w2 = (ushort_t*)alloc((size_t)768*3072*2);
  ushort_t* lnbuf  = (ushort_t*)alloc((size_t)8192*768*2);
  ushort_t* qkvbuf = (ushort_t*)alloc((size_t)3*96*1024*64*2);
  ushort_t* attno  = (ushort_t*)alloc((size_t)8192*768*2);
  ushort_t* hbuf   = qkvbuf;   // overlay: fc1 output reuses qkvbuf+attno (both dead)
  float* x1 = (float*)d_out;   // x1 lives in d_out (fp32)

  cvt_ln<<<15104, 256, 0, stream>>>(qkvw, projw, fc1w, fc2w, wq, wp, w1, w2,
                                    x, ln1w, ln1b, lnbuf);
  qkv_gemm8<<<288, 512, 0, stream>>>(lnbuf, wq, qkvb, qkvbuf, 768, 2304, 9);
  attn_kernel<<<dim3(16,96), 256, 0, stream>>>(qkvbuf, attno);
  proj_gemm<<<768, 256, 0, stream>>>(attno, wp, projb, x, x1, 768, 6);
  ln_kernel<<<8192, 192, 0, stream>>>(x1, ln2w, ln2b, lnbuf);
  fc1_gemm8<<<384, 512, 0, stream>>>(lnbuf, w1, fc1b, hbuf, 768, 3072, 12);
  fc2_gemm<<<768, 256, 0, stream>>>(hbuf, w2, fc2b, x1, (float*)d_out, 3072, 6);
}

// Round 25
// 297.257 us; speedup vs baseline: 1.0738x; 1.0193x over previous
//
#include <hip/hip_runtime.h>
#include <hip/hip_bf16.h>
#include <math.h>

typedef __attribute__((ext_vector_type(8))) short bf16x8;
typedef __attribute__((ext_vector_type(4))) float f32x4;
typedef unsigned short ushort_t;

#define GLOAD(srcp, dstp) __builtin_amdgcn_global_load_lds((const __attribute__((address_space(1))) void*)(srcp), (__attribute__((address_space(3))) void*)(dstp), 16, 0, 0)

// native bf16 convert (RNE)
__device__ inline ushort_t f2bfn(float f){
  union{ __bf16 h; ushort_t u; } c;
  c.h = (__bf16)f;
  return c.u;
}

// ---------------- merged: weight cvt (blocks 0..6911) + LN1 (blocks 6912..15103) ----------------
__global__ __launch_bounds__(256) void cvt_ln(const float* __restrict__ q, const float* __restrict__ p,
                                              const float* __restrict__ f1, const float* __restrict__ f2w,
                                              ushort_t* __restrict__ dq, ushort_t* __restrict__ dp,
                                              ushort_t* __restrict__ d1, ushort_t* __restrict__ d2,
                                              const float* __restrict__ x, const float* __restrict__ lw,
                                              const float* __restrict__ lb, ushort_t* __restrict__ lout){
  int bid = blockIdx.x;
  if(bid < 6912){
    int i4 = bid*256 + threadIdx.x;
    const float* src; ushort_t* dst; int off;
    if(i4 < 442368){ src=q;  dst=dq; off=i4; }
    else if(i4 < 589824){ src=p;  dst=dp; off=i4-442368; }
    else if(i4 < 1179648){ src=f1; dst=d1; off=i4-589824; }
    else { src=f2w; dst=d2; off=i4-1179648; }
    int i = off*4;
    float4 v = *(const float4*)(src+i);
    ushort4 o; o.x=f2bfn(v.x); o.y=f2bfn(v.y); o.z=f2bfn(v.z); o.w=f2bfn(v.w);
    *(ushort4*)(dst+i) = o;
  } else {
    int row = bid - 6912, t = threadIdx.x;
    __shared__ float ls[4], ls2[4];
    float4 v = (float4){0.f,0.f,0.f,0.f};
    float s = 0.f, s2 = 0.f;
    if(t < 192){
      v = *(const float4*)(x + (size_t)row*768 + t*4);
      s  = v.x+v.y+v.z+v.w;
      s2 = v.x*v.x+v.y*v.y+v.z*v.z+v.w*v.w;
    }
    for(int m=1;m<64;m<<=1){ s += __shfl_xor(s,m,64); s2 += __shfl_xor(s2,m,64); }
    int wv_ = t>>6;
    if((t&63)==0){ ls[wv_]=s; ls2[wv_]=s2; }
    __syncthreads();
    s = ls[0]+ls[1]+ls[2]+ls[3]; s2 = ls2[0]+ls2[1]+ls2[2]+ls2[3];
    float mu = s*(1.f/768.f);
    float var = s2*(1.f/768.f) - mu*mu;
    float rs = rsqrtf(var + 1e-5f);
    if(t < 192){
      float4 wv4 = *(const float4*)(lw + t*4);
      float4 bv4 = *(const float4*)(lb + t*4);
      ushort4 o;
      o.x = f2bfn((v.x-mu)*rs*wv4.x + bv4.x);
      o.y = f2bfn((v.y-mu)*rs*wv4.y + bv4.y);
      o.z = f2bfn((v.z-mu)*rs*wv4.z + bv4.z);
      o.w = f2bfn((v.w-mu)*rs*wv4.w + bv4.w);
      *(ushort4*)(lout + (size_t)row*768 + t*4) = o;
    }
  }
}

// ---------------- LayerNorm (LN2): 192 threads, float4 loads, ushort4 stores ----------------
__global__ __launch_bounds__(192) void ln_kernel(const float* __restrict__ x, const float* __restrict__ w,
                                                 const float* __restrict__ b, ushort_t* __restrict__ out){
  int row = blockIdx.x, t = threadIdx.x;
  const float4 v = *(const float4*)(x + (size_t)row*768 + t*4);
  float s  = v.x+v.y+v.z+v.w;
  float s2 = v.x*v.x+v.y*v.y+v.z*v.z+v.w*v.w;
  for(int m=1;m<64;m<<=1){ s += __shfl_xor(s,m,64); s2 += __shfl_xor(s2,m,64); }
  __shared__ float ls[3], ls2[3];
  int wv_ = t>>6;
  if((t&63)==0){ ls[wv_]=s; ls2[wv_]=s2; }
  __syncthreads();
  s = ls[0]+ls[1]+ls[2]; s2 = ls2[0]+ls2[1]+ls2[2];
  float mu = s*(1.f/768.f);
  float var = s2*(1.f/768.f) - mu*mu;
  float rs = rsqrtf(var + 1e-5f);
  float4 wv4 = *(const float4*)(w + t*4);
  float4 bv4 = *(const float4*)(b + t*4);
  ushort4 o;
  o.x = f2bfn((v.x-mu)*rs*wv4.x + bv4.x);
  o.y = f2bfn((v.y-mu)*rs*wv4.y + bv4.y);
  o.z = f2bfn((v.z-mu)*rs*wv4.z + bv4.z);
  o.w = f2bfn((v.w-mu)*rs*wv4.w + bv4.w);
  *(ushort4*)(out + (size_t)row*768 + t*4) = o;
}

// =======================================================================
// 8-phase 256x256 GEMM — FROZEN at round-20/22 verified state.
// =======================================================================
template<int EPI>
__device__ __forceinline__
void gemm8_body(const ushort_t* __restrict__ A, const ushort_t* __restrict__ BT,
                const float* __restrict__ bias, void* __restrict__ out,
                int K, int Nout, int nBN)
{
  __shared__ ushort_t lds[65536];
  ushort_t* As = lds;
  ushort_t* Bs = lds + 32768;
  const int tid = threadIdx.x;
  const int lane = tid & 63, wid = tid >> 6;
  const int wm = wid >> 2, wn = wid & 3;
  const int fq = lane >> 4, fr = lane & 15;

  const int nwg = (int)gridDim.x;
  const int bid = (int)blockIdx.x;
  const int wg = (bid & 7)*(nwg>>3) + (bid>>3);
  const int bm0 = (wg / nBN) << 8;
  const int bn0 = (wg % nBN) << 8;

  const int srow0 = tid >> 2;
  const int srow1 = 128 + srow0;
  const int sgc = ((tid & 3) ^ ((srow0 >> 1) & 3)) << 3;

  auto stageA = [&](int slot, int tile, int kh){
    const int k0 = (tile<<6) + (kh<<5);
    GLOAD(A + (size_t)(bm0 + srow0)*K + k0 + sgc, As + slot*8192 + (wid*64)*8);
    GLOAD(A + (size_t)(bm0 + srow1)*K + k0 + sgc, As + slot*8192 + (512 + wid*64)*8);
  };
  auto stageB = [&](int slot, int tile, int kh){
    const int k0 = (tile<<6) + (kh<<5);
    GLOAD(BT + (size_t)(bn0 + srow0)*K + k0 + sgc, Bs + slot*8192 + (wid*64)*8);
    GLOAD(BT + (size_t)(bn0 + srow1)*K + k0 + sgc, Bs + slot*8192 + (512 + wid*64)*8);
  };

  int aoff[8], boff[4];
  #pragma unroll
  for(int m=0;m<8;m++){ int r = wm*128 + m*16 + fr; aoff[m] = r*32 + ((fq ^ ((r>>1)&3))<<3); }
  #pragma unroll
  for(int n=0;n<4;n++){ int r = wn*64  + n*16 + fr; boff[n] = r*32 + ((fq ^ ((r>>1)&3))<<3); }

  f32x4 acc[8][4];
  #pragma unroll
  for(int m=0;m<8;m++)
    #pragma unroll
    for(int n=0;n<4;n++) acc[m][n] = (f32x4){0.f,0.f,0.f,0.f};

  const int NT = K >> 6;
  stageA(0,0,0); stageB(0,0,0);
  stageA(1,0,1); stageB(1,0,1);
  stageA(2,1,0); stageB(2,1,0);
  asm volatile("s_waitcnt vmcnt(4)" ::: "memory");
  __builtin_amdgcn_s_barrier();

  for(int g=0; g<NT; ++g){
    const int par = g & 1;
    const int sl0 = par*2, sl1 = par*2 + 1;
    const int osl1 = (par^1)*2 + 1;
    bf16x8 a[8], b0, b1;

    #pragma unroll
    for(int m=0;m<8;m++) a[m] = *(const bf16x8*)(As + sl0*8192 + aoff[m]);
    b0 = *(const bf16x8*)(Bs + sl0*8192 + boff[0]);
    b1 = *(const bf16x8*)(Bs + sl0*8192 + boff[1]);
    if(g+1 < NT) stageA(osl1, g+1, 1);
    __builtin_amdgcn_s_barrier();
    asm volatile("s_waitcnt lgkmcnt(0)" ::: "memory");
    __builtin_amdgcn_s_setprio(1);
    #pragma unroll
    for(int m=0;m<8;m++){
      acc[m][0] = __builtin_amdgcn_mfma_f32_16x16x32_bf16(a[m], b0, acc[m][0], 0,0,0);
      acc[m][1] = __builtin_amdgcn_mfma_f32_16x16x32_bf16(a[m], b1, acc[m][1], 0,0,0);
    }
    __builtin_amdgcn_s_setprio(0);

    b0 = *(const bf16x8*)(Bs + sl0*8192 + boff[2]);
    b1 = *(const bf16x8*)(Bs + sl0*8192 + boff[3]);
    if(g+1 < NT) stageB(osl1, g+1, 1);
    __builtin_amdgcn_s_barrier();
    asm volatile("s_waitcnt lgkmcnt(0)" ::: "memory");
    __builtin_amdgcn_s_setprio(1);
    #pragma unroll
    for(int m=0;m<8;m++){
      acc[m][2] = __builtin_amdgcn_mfma_f32_16x16x32_bf16(a[m], b0, acc[m][2], 0,0,0);
      acc[m][3] = __builtin_amdgcn_mfma_f32_16x16x32_bf16(a[m], b1, acc[m][3], 0,0,0);
    }
    __builtin_amdgcn_s_setprio(0);
    if(g+1 < NT){ asm volatile("s_waitcnt vmcnt(8)" ::: "memory"); }
    else        { asm volatile("s_waitcnt vmcnt(0)" ::: "memory"); }
    __builtin_amdgcn_s_barrier();

    #pragma unroll
    for(int m=0;m<8;m++) a[m] = *(const bf16x8*)(As + sl1*8192 + aoff[m]);
    b0 = *(const bf16x8*)(Bs + sl1*8192 + boff[0]);
    b1 = *(const bf16x8*)(Bs + sl1*8192 + boff[1]);
    if(g+2 < NT) stageA(sl0, g+2, 0);
    __builtin_amdgcn_s_barrier();
    asm volatile("s_waitcnt lgkmcnt(0)" ::: "memory");
    __builtin_amdgcn_s_setprio(1);
    #pragma unroll
    for(int m=0;m<8;m++){
      acc[m][0] = __builtin_amdgcn_mfma_f32_16x16x32_bf16(a[m], b0, acc[m][0], 0,0,0);
      acc[m][1] = __builtin_amdgcn_mfma_f32_16x16x32_bf16(a[m], b1, acc[m][1], 0,0,0);
    }
    __builtin_amdgcn_s_setprio(0);

    b0 = *(const bf16x8*)(Bs + sl1*8192 + boff[2]);
    b1 = *(const bf16x8*)(Bs + sl1*8192 + boff[3]);
    if(g+2 < NT) stageB(sl0, g+2, 0);
    __builtin_amdgcn_s_barrier();
    asm volatile("s_waitcnt lgkmcnt(0)" ::: "memory");
    __builtin_amdgcn_s_setprio(1);
    #pragma unroll
    for(int m=0;m<8;m++){
      acc[m][2] = __builtin_amdgcn_mfma_f32_16x16x32_bf16(a[m], b0, acc[m][2], 0,0,0);
      acc[m][3] = __builtin_amdgcn_mfma_f32_16x16x32_bf16(a[m], b1, acc[m][3], 0,0,0);
    }
    __builtin_amdgcn_s_setprio(0);
    if(g+2 < NT)      { asm volatile("s_waitcnt vmcnt(8)" ::: "memory"); }
    else if(g+1 < NT) { asm volatile("s_waitcnt vmcnt(4)" ::: "memory"); }
    else              { asm volatile("s_waitcnt vmcnt(0)" ::: "memory"); }
    __builtin_amdgcn_s_barrier();
  }

  __syncthreads();
  const float qscale = 0.18033688f;   // 0.125 * log2(e), folded into Q for attn
  const bool isQ = (EPI==0) && (bn0 < 768);
  #pragma unroll
  for(int m=0;m<8;m++){
    #pragma unroll
    for(int n=0;n<4;n++){
      int colL = wn*64 + n*16 + fr;
      float bv = bias[bn0 + colL];
      #pragma unroll
      for(int j=0;j<4;j++){
        int rowL = wm*128 + m*16 + fq*4 + j;
        float v = acc[m][n][j] + bv;
        if constexpr(EPI==2){
          float u = fminf(v*(1.0f + 0.044715f*v*v), 40.f);
          float e = exp2f(2.3020052f*u);
          v = v*e/(1.0f+e);
        }
        if(isQ) v *= qscale;
        lds[rowL*256 + (colL ^ (((rowL>>2)&3)<<4))] = f2bfn(v);
      }
    }
  }
  __syncthreads();
  const bool isV = (EPI==0) && (bn0 >= 1536);
  if(!isV){
    #pragma unroll 4
    for(int p=0;p<16;p++){
      int flat = tid + p*512;
      int row = flat>>5;
      int c8  = flat&31;
      int col = c8*8;
      bf16x8 v8 = *(const bf16x8*)&lds[row*256 + (col ^ (((row>>2)&3)<<4))];
      int rg = bm0 + row;
      if constexpr(EPI==0){
        int colg = bn0 + col;
        int which = colg >= 768 ? 1 : 0;
        int rem = colg - which*768;
        int hh = rem>>6, dh = rem&63;
        int bb = rg>>10, np = rg&1023;
        *(bf16x8*)&((ushort_t*)out)[(((size_t)(which*96 + bb*12 + hh)*1024 + np)<<6) + dh] = v8;
      } else {
        *(bf16x8*)&((ushort_t*)out)[(size_t)rg*(size_t)Nout + bn0 + col] = v8;
      }
    }
  } else {
    #pragma unroll 4
    for(int p=0;p<16;p++){
      int flat = tid + p*512;
      int dL = flat>>5;
      int t8 = (flat&31)*8;
      ushort_t tmp[8];
      #pragma unroll
      for(int i=0;i<8;i++){
        int row = t8 + i;
        tmp[i] = lds[row*256 + (dL ^ (((row>>2)&3)<<4))];
      }
      int dg = bn0 - 1536 + dL;
      int hh = dg>>6, dh = dg&63;
      int tok0 = bm0 + t8;
      int bb = tok0>>10, np = tok0&1023;
      *(bf16x8*)&((ushort_t*)out)[((size_t)(192 + bb*12 + hh)*65536) + dh*1024 + np] = *(bf16x8*)tmp;
    }
  }
}

__global__ __launch_bounds__(512, 2)
void qkv_gemm8(const ushort_t* __restrict__ A, const ushort_t* __restrict__ BT,
               const float* __restrict__ bias, void* __restrict__ out, int K, int Nout, int nBN)
{ gemm8_body<0>(A, BT, bias, out, K, Nout, nBN); }

__global__ __launch_bounds__(512, 2)
void fc1_gemm8(const ushort_t* __restrict__ A, const ushort_t* __restrict__ BT,
               const float* __restrict__ bias, void* __restrict__ out, int K, int Nout, int nBN)
{ gemm8_body<2>(A, BT, bias, out, K, Nout, nBN); }

// ---------------- 64x128 GEMM (EPI1: +resid fp32) for proj / fc2 — FROZEN (verified r16) ----------------
__device__ __forceinline__
void gemm_body_epi1(const ushort_t* __restrict__ A, const ushort_t* __restrict__ BT,
                    const float* __restrict__ bias, const float* __restrict__ resid,
                    float* __restrict__ out, int K, int nBN)
{
  __shared__ ushort_t Asm[4][64*32];
  __shared__ ushort_t Bsm[4][128*32];
  const int nwg = (int)gridDim.x;
  const int bid = (int)blockIdx.x;
  const int wg = (bid & 7)*(nwg>>3) + (bid>>3);
  const int bm0 = (wg / nBN) * 64;
  const int bn0 = (wg % nBN) * 128;
  const int tid = threadIdx.x;
  const int lane = tid & 63;
  const int wid = tid >> 6;
  const int wn = wid;
  const int fq = lane>>4, fr = lane&15;

  const int rA = tid>>2;
  const int cAs = ((tid&3) ^ ((rA>>1)&3))<<3;
  const int r0 = wid*32 + (lane>>2);
  const int r1 = r0 + 16;
  const int cBs = ((lane&3) ^ ((r0>>1)&3))<<3;

  f32x4 acc[4][2];
  for(int m=0;m<4;m++) for(int n=0;n<2;n++) acc[m][n] = (f32x4){0.f,0.f,0.f,0.f};

  auto STAGE = [&](int buf, int k0){
    GLOAD(A  + (size_t)(bm0+rA)*K + k0 + cAs, &Asm[buf][wid*512]);
    GLOAD(BT + (size_t)(bn0+r0)*K + k0 + cBs, &Bsm[buf][(wid*2)*512]);
    GLOAD(BT + (size_t)(bn0+r1)*K + k0 + cBs, &Bsm[buf][(wid*2+1)*512]);
  };

  int aoff[4], boff[2];
  #pragma unroll
  for(int m=0;m<4;m++){ int r = m*16 + fr; aoff[m] = r*32 + ((fq ^ ((r>>1)&3))<<3); }
  #pragma unroll
  for(int n=0;n<2;n++){ int r = wn*32 + n*16 + fr; boff[n] = r*32 + ((fq ^ ((r>>1)&3))<<3); }

  const int NT = K>>5;
  STAGE(0, 0);
  STAGE(1, 32);
  STAGE(2, 64);
  asm volatile("s_waitcnt vmcnt(6)" ::: "memory");
  __builtin_amdgcn_s_barrier();

  int cur = 0;
  for(int kt=0; kt<NT; ++kt){
    if(kt+3 < NT) STAGE((cur+3)&3, (kt+3)<<5);
    bf16x8 af[4], bfr[2];
    #pragma unroll
    for(int m=0;m<4;m++)
      af[m] = *(const bf16x8*)(&Asm[cur][aoff[m]]);
    #pragma unroll
    for(int n=0;n<2;n++)
      bfr[n] = *(const bf16x8*)(&Bsm[cur][boff[n]]);
    #pragma unroll
    for(int m=0;m<4;m++)
      #pragma unroll
      for(int n=0;n<2;n++)
        acc[m][n] = __builtin_amdgcn_mfma_f32_16x16x32_bf16(af[m], bfr[n], acc[m][n], 0,0,0);
    if(kt+1 < NT){
      if(kt+3 < NT)      { asm volatile("s_waitcnt vmcnt(6)" ::: "memory"); }
      else if(kt+2 < NT) { asm volatile("s_waitcnt vmcnt(3)" ::: "memory"); }
      else               { asm volatile("s_waitcnt vmcnt(0)" ::: "memory"); }
      __builtin_amdgcn_s_barrier();
    }
    cur = (cur+1)&3;
  }

  for(int m=0;m<4;m++){
    int row0 = bm0 + m*16 + fq*4;
    for(int n=0;n<2;n++){
      int col = bn0 + wn*32 + n*16 + fr;
      float bv = bias[col];
      for(int j=0;j<4;j++){
        int r = row0 + j;
        float v = acc[m][n][j] + bv + resid[(size_t)r*768 + col];
        out[(size_t)r*768 + col] = v;
      }
    }
  }
}

__global__ __launch_bounds__(256)
void proj_gemm(const ushort_t* __restrict__ A, const ushort_t* __restrict__ BT,
               const float* __restrict__ bias, const float* __restrict__ resid,
               float* __restrict__ out, int K, int nBN)
{ gemm_body_epi1(A, BT, bias, resid, out, K, nBN); }

__global__ __launch_bounds__(256)
void fc2_gemm(const ushort_t* __restrict__ A, const ushort_t* __restrict__ BT,
              const float* __restrict__ bias, const float* __restrict__ resid,
              float* __restrict__ out, int K, int nBN)
{ gemm_body_epi1(A, BT, bias, resid, out, K, nBN); }

// ---------------- Flash attention — ROUND-25: QBLK=128 via 8 warps/block (512 threads).
// Per-warp code identical to verified round-23 kernel (16 q rows each; Psm warp-private).
// Halves per-thread staging (1 K-chunk + 1 V-chunk each) and K/V L2 re-reads (8 blocks/head).
// LDS 48KB -> 3 blocks/CU x 8 waves = 24 waves/CU (was 16).
__global__ __launch_bounds__(512, 6)
void attn_kernel(const ushort_t* __restrict__ qkv, ushort_t* __restrict__ outp)
{
  __shared__ ushort_t Ksm[2][64*64];
  __shared__ ushort_t Vt[2][64*64];
  __shared__ ushort_t Psm[8][16*64];
  const int bh = blockIdx.y;
  const int q0 = blockIdx.x*128;
  const int tid = threadIdx.x, lane = tid&63, wid = tid>>6;   // wid 0..7
  const int fq = lane>>4, fr = lane&15;
  const ushort_t* Qb = qkv + ((size_t)bh*1024)*64;
  const ushort_t* Kb = qkv + ((size_t)(96 + bh)*1024)*64;
  const ushort_t* Vb = qkv + ((size_t)(192 + bh))*65536;

  bf16x8 ones;
  #pragma unroll
  for(int i=0;i<8;i++) ones[i] = (short)0x3F80;

  bf16x8 qf[2];
  {
    int qr = q0 + wid*16 + fr;
    qf[0] = *(const bf16x8*)(Qb + (size_t)qr*64 +      fq*8);
    qf[1] = *(const bf16x8*)(Qb + (size_t)qr*64 + 32 + fq*8);
  }
  f32x4 o[4];
  for(int dt=0;dt<4;dt++) o[dt] = (f32x4){0.f,0.f,0.f,0.f};
  float lrun[4];
  for(int j=0;j<4;j++) lrun[j]=0.f;

  // staging: 512 threads cover 64 rows x 8 granules, ONE chunk per matrix per thread
  const int sr = tid>>3, sg = tid&7;
  const int sc = sg*8;
  const int swc = ((sg ^ (sr&7))<<3);

  bf16x8 k0r = *(const bf16x8*)(Kb + (size_t)sr*64 + sc);
  bf16x8 v0r = *(const bf16x8*)(Vb + (size_t)sr*1024 + sc);
  *(bf16x8*)(Ksm[0] + sr*64 + swc) = k0r;
  *(bf16x8*)(Vt[0]  + sr*64 + swc) = v0r;

  int cur = 0;
  for(int kt=0; kt<16; kt++){
    __syncthreads();
    if(kt+1 < 16){
      int kv1 = (kt+1)*64;
      k0r = *(const bf16x8*)(Kb + (size_t)(kv1+sr)*64 + sc);
      v0r = *(const bf16x8*)(Vb + (size_t)sr*1024 + kv1 + sc);
    }

    f32x4 s[4];
    for(int ct=0;ct<4;ct++){
      int krow = ct*16 + fr;
      bf16x8 kf0 = *(const bf16x8*)(Ksm[cur] + krow*64 + (((fq  ) ^ (fr&7))<<3));
      bf16x8 kf1 = *(const bf16x8*)(Ksm[cur] + krow*64 + (((4+fq) ^ (fr&7))<<3));
      f32x4 z = (f32x4){0.f,0.f,0.f,0.f};
      z = __builtin_amdgcn_mfma_f32_16x16x32_bf16(qf[0], kf0, z, 0,0,0);
      z = __builtin_amdgcn_mfma_f32_16x16x32_bf16(qf[1], kf1, z, 0,0,0);
      s[ct] = z;
    }

    // static softmax, scale pre-folded into Q: P = exp2(s)
    #pragma unroll
    for(int ct=0;ct<4;ct++){
      #pragma unroll
      for(int j=0;j<4;j++){
        float p = exp2f(s[ct][j]);
        int g = (ct*2 + (fr>>3)) ^ (fq<<1);
        Psm[wid][(fq*4 + j)*64 + g*8 + (fr&7)] = f2bfn(p);
      }
    }

    bf16x8 pf[2];
    {
      int key = ((fr>>2)&3)<<1;
      pf[0] = *(const bf16x8*)(&Psm[wid][fr*64 + (((0*4+fq)^key)<<3)]);
      pf[1] = *(const bf16x8*)(&Psm[wid][fr*64 + (((1*4+fq)^key)<<3)]);
    }
    f32x4 o5 = (f32x4){0.f,0.f,0.f,0.f};
    o5 = __builtin_amdgcn_mfma_f32_16x16x32_bf16(pf[0], ones, o5, 0,0,0);
    o5 = __builtin_amdgcn_mfma_f32_16x16x32_bf16(pf[1], ones, o5, 0,0,0);
    #pragma unroll
    for(int j=0;j<4;j++) lrun[j] += o5[j];

    for(int dt=0;dt<4;dt++){
      int vrow = dt*16 + fr;
      for(int kc=0;kc<2;kc++){
        bf16x8 vf = *(const bf16x8*)(Vt[cur] + vrow*64 + (((kc*4+fq) ^ (fr&7))<<3));
        o[dt] = __builtin_amdgcn_mfma_f32_16x16x32_bf16(pf[kc], vf, o[dt], 0,0,0);
      }
    }

    if(kt+1 < 16){
      *(bf16x8*)(Ksm[cur^1] + sr*64 + swc) = k0r;
      *(bf16x8*)(Vt[cur^1]  + sr*64 + swc) = v0r;
    }
    cur ^= 1;
  }

  int b = bh/12, h = bh%12;
  for(int dt=0;dt<4;dt++){
    for(int j=0;j<4;j++){
      int qr = q0 + wid*16 + fq*4 + j;
      float v = o[dt][j] / lrun[j];
      outp[(size_t)(b*1024 + qr)*768 + h*64 + dt*16 + fr] = f2bfn(v);
    }
  }
}

extern "C" void kernel_launch(void* const* d_in, const int* in_sizes, int n_in,
                              void* d_out, int out_size, void* d_ws, size_t ws_size,
                              hipStream_t stream)
{
  const float* x     = (const float*)d_in[0];
  const float* ln1w  = (const float*)d_in[1];
  const float* ln1b  = (const float*)d_in[2];
  const float* qkvw  = (const float*)d_in[3];
  const float* qkvb  = (const float*)d_in[4];
  const float* projw = (const float*)d_in[5];
  const float* projb = (const float*)d_in[6];
  const float* ln2w  = (const float*)d_in[7];
  const float* ln2b  = (const float*)d_in[8];
  const float* fc1w  = (const float*)d_in[9];
  const float* fc1b  = (const float*)d_in[10];
  const float* fc2w  = (const float*)d_in[11];
  const float* fc2b  = (const float*)d_in[12];

  char* ws = (char*)d_ws;
  size_t off = 0;
  auto alloc = [&](size_t bytes){ char* p = ws + off; off += (bytes + 255) & ~255ULL; return p; };
  ushort_t* wq = (ushort_t*)alloc((size_t)2304*768*2);
  ushort_t* wp = (ushort_t*)alloc((size_t)768*768*2);
  ushort_t* w1 = (ushort_t*)alloc((size_t)3072*768*2);
  ushort_t* w2 = (ushort_t*)alloc((size_t)768*3072*2);
  ushort_t* lnbuf  = (ushort_t*)alloc((size_t)8192*768*2);
  ushort_t* qkvbuf = (ushort_t*)alloc((size_t)3*96*1024*64*2);
  ushort_t* attno  = (ushort_t*)alloc((size_t)8192*768*2);
  ushort_t* hbuf   = qkvbuf;   // overlay: fc1 output reuses qkvbuf+attno (both dead)
  float* x1 = (float*)d_out;   // x1 lives in d_out (fp32)

  cvt_ln<<<15104, 256, 0, stream>>>(qkvw, projw, fc1w, fc2w, wq, wp, w1, w2,
                                    x, ln1w, ln1b, lnbuf);
  qkv_gemm8<<<288, 512, 0, stream>>>(lnbuf, wq, qkvb, qkvbuf, 768, 2304, 9);
  attn_kernel<<<dim3(8,96), 512, 0, stream>>>(qkvbuf, attno);
  proj_gemm<<<768, 256, 0, stream>>>(attno, wp, projb, x, x1, 768, 6);
  ln_kernel<<<8192, 192, 0, stream>>>(x1, ln2w, ln2b, lnbuf);
  fc1_gemm8<<<384, 512, 0, stream>>>(lnbuf, w1, fc1b, hbuf, 768, 3072, 12);
  fc2_gemm<<<768, 256, 0, stream>>>(hbuf, w2, fc2b, x1, (float*)d_out, 3072, 6);
}